// Round 16
// baseline (417.954 us; speedup 1.0000x reference)
//
#include <hip/hip_runtime.h>
#include <math.h>

#define NB 4
#define TT 16
#define NNODE 1000
#define FIN 8
#define EE 8000
#define EP 9000          // E + N self loops
#define EPAD 16384       // max padded edges (pad rows to mult of 8)
#define HID 64
#define HEADS 4
#define NL 5
#define GG (NB*TT)       // 64 graphs
#define ROWS (GG*NNODE)  // 64000
#define HCOL (HEADS*HID) // 256
#define KGI (NNODE*HID)  // 64000
#define GOUT 192         // 3*HID
#define GIK 128          // K-slice per gi-gemm block
#define KSPLIT (KGI/GIK) // 500 partial slabs
#define GOSZ (GG*GOUT)   // 12288
#define WPSZ (8*4*64*8)  // 16384 packed W elems per layer
#define NBLK 63          // node blocks per graph (63*16 = 1008 >= 1000)

typedef unsigned short u16;
typedef __attribute__((ext_vector_type(8))) short short8;
typedef __attribute__((ext_vector_type(4))) float f32x4;

__device__ inline u16 f2bf(float f) {
    unsigned int u = __float_as_uint(f);
    unsigned int r = u + 0x7FFFu + ((u >> 16) & 1u);   // RNE
    return (u16)(r >> 16);
}
__device__ inline float bf2f(u16 h) {
    return __uint_as_float(((unsigned int)h) << 16);
}
__device__ inline ushort4 bfhi4(float4 a) {
    ushort4 r; r.x = f2bf(a.x); r.y = f2bf(a.y); r.z = f2bf(a.z); r.w = f2bf(a.w); return r;
}
__device__ inline ushort4 bflo4(float4 a, ushort4 h) {
    ushort4 r;
    r.x = f2bf(a.x - bf2f(h.x)); r.y = f2bf(a.y - bf2f(h.y));
    r.z = f2bf(a.z - bf2f(h.z)); r.w = f2bf(a.w - bf2f(h.w));
    return r;
}

// ---------------- edge prep ----------------
__global__ void k_build_edges(const int* __restrict__ eidx, int* __restrict__ src_e,
                              int* __restrict__ dst_e, int* __restrict__ deg, int* __restrict__ fill) {
    int i = blockIdx.x * blockDim.x + threadIdx.x;
    if (i < EP) {
        int s, d;
        if (i < EE) { s = eidx[i]; d = eidx[EE + i]; }
        else { s = i - EE; d = i - EE; }
        src_e[i] = s; dst_e[i] = d;
    }
    if (i < NNODE) { deg[i] = 0; fill[i] = 0; }
}

__global__ void k_csr_count(const int* __restrict__ dst_e, int* __restrict__ deg) {
    int i = blockIdx.x * blockDim.x + threadIdx.x;
    if (i < EP) atomicAdd(&deg[dst_e[i]], 1);
}

// parallel inclusive scan of PADDED degrees (pad to multiple of 8)
__global__ __launch_bounds__(256) void k_csr_scan(const int* __restrict__ deg, int* __restrict__ rowptr_p) {
    __shared__ int s[1024];
    int tid = threadIdx.x;
    for (int i = tid; i < 1024; i += 256) s[i] = (i < NNODE) ? ((deg[i] + 7) & ~7) : 0;
    __syncthreads();
    for (int off = 1; off < 1024; off <<= 1) {
        int t[4];
        #pragma unroll
        for (int q = 0; q < 4; q++) { int i = tid + 256 * q; t[q] = (i >= off) ? s[i - off] : 0; }
        __syncthreads();
        #pragma unroll
        for (int q = 0; q < 4; q++) { int i = tid + 256 * q; s[i] += t[q]; }
        __syncthreads();
    }
    for (int i = tid; i < NNODE; i += 256) rowptr_p[i + 1] = s[i];
    if (tid == 0) rowptr_p[0] = 0;
}

// fill CSR + pad slots (disjoint writes; pad needs only rowptr_p/deg, no ordering vs fill)
__global__ void k_csr_fill(const int* __restrict__ src_e, const int* __restrict__ dst_e,
                           const int* __restrict__ rowptr_p, const int* __restrict__ deg,
                           int* __restrict__ fill, int* __restrict__ csr_src) {
    int i = blockIdx.x * blockDim.x + threadIdx.x;
    if (i < EP) {
        int d = dst_e[i];
        int pos = atomicAdd(&fill[d], 1);
        csr_src[rowptr_p[d] + pos] = src_e[i];
    }
    if (i < NNODE) {
        int rs = rowptr_p[i], re = rowptr_p[i + 1];
        for (int j = rs + deg[i]; j < re; j++) csr_src[j] = i;
    }
}

// ---------------- precompute wa/wd: wa[l][j][h] = sum_c W_l[j, h*64+c] * a_src[l,h,c] ----------------
__global__ void k_wa(const float* __restrict__ Wg, const float* __restrict__ a_src,
                     const float* __restrict__ a_dst, float* __restrict__ wa, float* __restrict__ wd) {
    int t = blockIdx.x * 256 + threadIdx.x;      // 2*NL*HID*HEADS = 2560
    if (t >= 2 * NL * HID * HEADS) return;
    int kind = t >= NL * HID * HEADS;
    int u = t - kind * NL * HID * HEADS;
    int l = u >> 8;
    int rem = u & 255;
    int j = rem >> 2, hd = rem & 3;
    const float* a = (kind ? a_dst : a_src) + (size_t)l * HCOL + hd * HID;
    const float* Wl = Wg + (size_t)l * HID * HCOL + (size_t)j * HCOL + hd * HID;
    float acc = 0.f;
    #pragma unroll 8
    for (int c = 0; c < HID; c++) acc += Wl[c] * a[c];
    float* out = kind ? wd : wa;
    out[(size_t)l * HCOL + j * 4 + hd] = acc;
}

// ---------------- pack W into MFMA B-frag order, split bf16 hi/lo ----------------
// B frag layout (16x16x32): lane needs B[k=(lane>>4)*8+j][col=lane&15]
// wp[((l*8+ks)*4+ct)*512 + lane*8 + j] = W'[ks*32+(lane>>4)*8+j][ct*16+(lane&15)]
// where W'[k][c'] = Wg[l][k&63][(k>>6)*64+c']
__global__ void k_wpack(const float* __restrict__ Wg, u16* __restrict__ wph, u16* __restrict__ wpl) {
    int t = blockIdx.x * 256 + threadIdx.x;      // NL*WPSZ = 81920
    if (t >= NL * WPSZ) return;
    int j    = t & 7;
    int lane = (t >> 3) & 63;
    int ct   = (t >> 9) & 3;
    int ks   = (t >> 11) & 7;
    int l    = t >> 14;
    int k = ks * 32 + (lane >> 4) * 8 + j;
    int c = ct * 16 + (lane & 15);
    float v = Wg[(size_t)l * HID * HCOL + (size_t)(k & 63) * HCOL + (k >> 6) * 64 + c];
    u16 h = f2bf(v);
    wph[t] = h;
    wpl[t] = f2bf(v - bf2f(h));
}

// ---------------- input projection + fused layer-0 ls/ld ----------------
__global__ void k_input_fc(const float* __restrict__ xseq, const float4* __restrict__ Win4,
                           const float4* __restrict__ b_in4, const float4* __restrict__ wa04,
                           const float4* __restrict__ wd04, float4* __restrict__ x0,
                           float4* __restrict__ ls4, float4* __restrict__ ld4) {
    int idx = blockIdx.x * 256 + threadIdx.x;   // ROWS*16 threads
    int r = idx >> 4, c4 = idx & 15;
    float4 acc = b_in4[c4];
    #pragma unroll
    for (int k = 0; k < FIN; k++) {
        float xv = xseq[r * FIN + k];
        float4 w = Win4[k * 16 + c4];
        acc.x += xv * w.x; acc.y += xv * w.y; acc.z += xv * w.z; acc.w += xv * w.w;
    }
    x0[idx] = acc;
    float xr[4] = {acc.x, acc.y, acc.z, acc.w};
    float4 pls = make_float4(0.f, 0.f, 0.f, 0.f);
    float4 pld = make_float4(0.f, 0.f, 0.f, 0.f);
    #pragma unroll
    for (int jj = 0; jj < 4; jj++) {
        float4 wa_j = wa04[c4 * 4 + jj];
        float4 wd_j = wd04[c4 * 4 + jj];
        pls.x += xr[jj] * wa_j.x; pls.y += xr[jj] * wa_j.y;
        pls.z += xr[jj] * wa_j.z; pls.w += xr[jj] * wa_j.w;
        pld.x += xr[jj] * wd_j.x; pld.y += xr[jj] * wd_j.y;
        pld.z += xr[jj] * wd_j.z; pld.w += xr[jj] * wd_j.w;
    }
    #pragma unroll
    for (int o = 1; o < 16; o <<= 1) {
        pls.x += __shfl_xor(pls.x, o, 64); pls.y += __shfl_xor(pls.y, o, 64);
        pls.z += __shfl_xor(pls.z, o, 64); pls.w += __shfl_xor(pls.w, o, 64);
        pld.x += __shfl_xor(pld.x, o, 64); pld.y += __shfl_xor(pld.y, o, 64);
        pld.z += __shfl_xor(pld.z, o, 64); pld.w += __shfl_xor(pld.w, o, 64);
    }
    if (c4 == 0) {
        ls4[r] = pls;
        ld4[r] = pld;
    }
}

// ---------------- FUSED GAT layer, 16-node blocks for occupancy ----------------
// Block = 256 thr, 16 nodes. Grid = 64 graphs x 63 blocks = 4032 (last 8 node slots invalid).
// Agg: 4 waves x 4 nodes, SINGLE SHOT (no it2 loop -> no cross-iteration LDS hazard; the
// wave-synchronous softmax->gather pattern is the R8-verified unfused one, barrier-free).
// LDS ~35.3 KB -> 4 blocks/CU (16 waves/CU, 2x the 32-node version's TLP).
// GEMM: wave = 16 rows x 16 cols (ct = wid), A from LDS, B = packed W. 3-term split-bf16.
// NOTE: reads layer-l state, writes layer-(l+1) state -> ping-pong buffers.
__global__ __launch_bounds__(256) void k_gat_fused(
        const float4* __restrict__ x4, const float4* __restrict__ ls4, const float4* __restrict__ ld4,
        const int* __restrict__ rowptr_p, const int* __restrict__ csr_src, const int* __restrict__ deg,
        const u16* __restrict__ wph, const u16* __restrict__ wpl, const float* __restrict__ bg,
        float* __restrict__ xout, const float4* __restrict__ wa4, const float4* __restrict__ wd4,
        float4* __restrict__ lso4, float4* __restrict__ ldo4) {
    __shared__ u16 yhs[16][264];          // 8.25 KB
    __shared__ u16 yls[16][264];          // 8.25 KB
    __shared__ float s_e[4][4][264];      // 16.9 KB (aliased as ls/ld partials in epilogue)
    __shared__ u16 s_src[4][4][64];       // 2 KB
    __shared__ float s_den[4][4][4];
    int b = blockIdx.x;
    int xcd = b & 7, sb = b >> 3;         // XCD round-robin
    int g = xcd + 8 * (sb / NBLK);        // graph 0..63
    int nb = (sb % NBLK) * 16;            // node base within graph
    int tid = threadIdx.x;
    int wid = tid >> 6, lane = tid & 63;
    int nsub = lane >> 4;                 // node slot 0..3
    int j0 = lane & 15;
    int c4 = lane & 15;
    const float4* lsg = ls4 + (size_t)g * NNODE;
    const float4* xg = x4 + (size_t)g * NNODE * 16 + c4;

    // ---------- aggregation: wave wid owns nodes nb + wid*4 .. +3 (single shot) ----------
    int n_l = wid * 4 + nsub;             // local row 0..15
    int n_s = nb + n_l;
    int valid = n_s < NNODE;
    int n_c = valid ? n_s : (NNODE - 1);
    int rs = rowptr_p[n_c];
    int dgp = valid ? (rowptr_p[n_c + 1] - rs) : 0;
    int dg = valid ? deg[n_c] : 0;
    int dg16 = (dgp + 15) & ~15;
    if (dg16 > 64) dg16 = 64;
    if (dgp > 64) dgp = 64;
    if (dg > 64) dg = 64;
    float4 ldv = ld4[(size_t)g * NNODE + n_c];

    // pass A: logits + running max
    float4 mx = make_float4(-1e30f, -1e30f, -1e30f, -1e30f);
    for (int base = 0; base < dg16; base += 16) {
        int j = base + j0;
        int sv = n_c;
        if (j < dgp) sv = csr_src[rs + j];
        s_src[wid][nsub][j] = (u16)sv;
        float4 lo = make_float4(-1e30f, -1e30f, -1e30f, -1e30f);
        if (j < dg) {
            float4 t = lsg[sv];
            t.x += ldv.x; t.y += ldv.y; t.z += ldv.z; t.w += ldv.w;
            t.x = fmaxf(t.x, 0.2f * t.x); t.y = fmaxf(t.y, 0.2f * t.y);
            t.z = fmaxf(t.z, 0.2f * t.z); t.w = fmaxf(t.w, 0.2f * t.w);
            lo = t;
            mx.x = fmaxf(mx.x, lo.x); mx.y = fmaxf(mx.y, lo.y);
            mx.z = fmaxf(mx.z, lo.z); mx.w = fmaxf(mx.w, lo.w);
        }
        *reinterpret_cast<float4*>(&s_e[wid][nsub][j * 4]) = lo;
    }
    #pragma unroll
    for (int o = 1; o < 16; o <<= 1) {
        mx.x = fmaxf(mx.x, __shfl_xor(mx.x, o, 64));
        mx.y = fmaxf(mx.y, __shfl_xor(mx.y, o, 64));
        mx.z = fmaxf(mx.z, __shfl_xor(mx.z, o, 64));
        mx.w = fmaxf(mx.w, __shfl_xor(mx.w, o, 64));
    }
    // pass B: exp + denominator
    float4 den = make_float4(0.f, 0.f, 0.f, 0.f);
    for (int base = 0; base < dg16; base += 16) {
        int j = base + j0;
        float4 e = make_float4(0.f, 0.f, 0.f, 0.f);
        if (j < dg) {
            float4 lo = *reinterpret_cast<const float4*>(&s_e[wid][nsub][j * 4]);
            e.x = __expf(lo.x - mx.x);
            e.y = __expf(lo.y - mx.y);
            e.z = __expf(lo.z - mx.z);
            e.w = __expf(lo.w - mx.w);
        }
        den.x += e.x; den.y += e.y; den.z += e.z; den.w += e.w;
        *reinterpret_cast<float4*>(&s_e[wid][nsub][j * 4]) = e;
    }
    #pragma unroll
    for (int o = 1; o < 16; o <<= 1) {
        den.x += __shfl_xor(den.x, o, 64);
        den.y += __shfl_xor(den.y, o, 64);
        den.z += __shfl_xor(den.z, o, 64);
        den.w += __shfl_xor(den.w, o, 64);
    }
    if (j0 == 0) *reinterpret_cast<float4*>(&s_den[wid][nsub][0]) = den;

    // gather: lane (nsub,c4) owns one node's col slice, all 4 heads (wave-synchronous reads)
    {
        float4 a0 = make_float4(0.f, 0.f, 0.f, 0.f);
        float4 a1 = a0, a2 = a0, a3 = a0;
        const float* ep = &s_e[wid][nsub][0];
        const u16* sp = &s_src[wid][nsub][0];
        int dg4 = (dg + 3) & ~3;
        int q = 0;
        for (; q + 8 <= dg4; q += 8) {
            int sj[8]; float4 ev[8], xv[8];
            #pragma unroll
            for (int u = 0; u < 8; u++) sj[u] = sp[q + u];
            #pragma unroll
            for (int u = 0; u < 8; u++) xv[u] = xg[(size_t)sj[u] * 16];
            #pragma unroll
            for (int u = 0; u < 8; u++) ev[u] = *reinterpret_cast<const float4*>(&ep[(q + u) * 4]);
            #pragma unroll
            for (int u = 0; u < 8; u++) {
                a0.x += ev[u].x * xv[u].x; a0.y += ev[u].x * xv[u].y;
                a0.z += ev[u].x * xv[u].z; a0.w += ev[u].x * xv[u].w;
                a1.x += ev[u].y * xv[u].x; a1.y += ev[u].y * xv[u].y;
                a1.z += ev[u].y * xv[u].z; a1.w += ev[u].y * xv[u].w;
                a2.x += ev[u].z * xv[u].x; a2.y += ev[u].z * xv[u].y;
                a2.z += ev[u].z * xv[u].z; a2.w += ev[u].z * xv[u].w;
                a3.x += ev[u].w * xv[u].x; a3.y += ev[u].w * xv[u].y;
                a3.z += ev[u].w * xv[u].z; a3.w += ev[u].w * xv[u].w;
            }
        }
        if (q < dg4) {
            int sj[4]; float4 ev[4], xv[4];
            #pragma unroll
            for (int u = 0; u < 4; u++) sj[u] = sp[q + u];
            #pragma unroll
            for (int u = 0; u < 4; u++) xv[u] = xg[(size_t)sj[u] * 16];
            #pragma unroll
            for (int u = 0; u < 4; u++) ev[u] = *reinterpret_cast<const float4*>(&ep[(q + u) * 4]);
            #pragma unroll
            for (int u = 0; u < 4; u++) {
                a0.x += ev[u].x * xv[u].x; a0.y += ev[u].x * xv[u].y;
                a0.z += ev[u].x * xv[u].z; a0.w += ev[u].x * xv[u].w;
                a1.x += ev[u].y * xv[u].x; a1.y += ev[u].y * xv[u].y;
                a1.z += ev[u].y * xv[u].z; a1.w += ev[u].y * xv[u].w;
                a2.x += ev[u].z * xv[u].x; a2.y += ev[u].z * xv[u].y;
                a2.z += ev[u].z * xv[u].z; a2.w += ev[u].z * xv[u].w;
                a3.x += ev[u].w * xv[u].x; a3.y += ev[u].w * xv[u].y;
                a3.z += ev[u].w * xv[u].z; a3.w += ev[u].w * xv[u].w;
            }
        }
        float4 dv = *reinterpret_cast<const float4*>(&s_den[wid][nsub][0]);
        float i0 = 1.f / (dv.x + 1e-16f), i1 = 1.f / (dv.y + 1e-16f);
        float i2 = 1.f / (dv.z + 1e-16f), i3 = 1.f / (dv.w + 1e-16f);
        a0.x *= i0; a0.y *= i0; a0.z *= i0; a0.w *= i0;
        a1.x *= i1; a1.y *= i1; a1.z *= i1; a1.w *= i1;
        a2.x *= i2; a2.y *= i2; a2.z *= i2; a2.w *= i2;
        a3.x *= i3; a3.y *= i3; a3.z *= i3; a3.w *= i3;
        ushort4 h0 = bfhi4(a0), h1 = bfhi4(a1), h2 = bfhi4(a2), h3 = bfhi4(a3);
        *reinterpret_cast<ushort4*>(&yhs[n_l][0 * 64 + c4 * 4]) = h0;
        *reinterpret_cast<ushort4*>(&yhs[n_l][1 * 64 + c4 * 4]) = h1;
        *reinterpret_cast<ushort4*>(&yhs[n_l][2 * 64 + c4 * 4]) = h2;
        *reinterpret_cast<ushort4*>(&yhs[n_l][3 * 64 + c4 * 4]) = h3;
        *reinterpret_cast<ushort4*>(&yls[n_l][0 * 64 + c4 * 4]) = bflo4(a0, h0);
        *reinterpret_cast<ushort4*>(&yls[n_l][1 * 64 + c4 * 4]) = bflo4(a1, h1);
        *reinterpret_cast<ushort4*>(&yls[n_l][2 * 64 + c4 * 4]) = bflo4(a2, h2);
        *reinterpret_cast<ushort4*>(&yls[n_l][3 * 64 + c4 * 4]) = bflo4(a3, h3);
    }
    __syncthreads();

    // ---------- GEMM: wave wid handles col-tile ct = wid; rows 0..15 ----------
    int arow = lane & 15, kg = lane >> 4;
    f32x4 acc0 = {0.f, 0.f, 0.f, 0.f};
    const short8* bh8 = reinterpret_cast<const short8*>(wph) + lane;
    const short8* bl8 = reinterpret_cast<const short8*>(wpl) + lane;
    #pragma unroll
    for (int ks = 0; ks < 8; ks++) {
        short8 ah = *reinterpret_cast<const short8*>(&yhs[arow][ks * 32 + kg * 8]);
        short8 al = *reinterpret_cast<const short8*>(&yls[arow][ks * 32 + kg * 8]);
        short8 bh = bh8[(size_t)(ks * 4 + wid) * 64];
        short8 bl = bl8[(size_t)(ks * 4 + wid) * 64];
        acc0 = __builtin_amdgcn_mfma_f32_16x16x32_bf16(ah, bh, acc0, 0, 0, 0);
        acc0 = __builtin_amdgcn_mfma_f32_16x16x32_bf16(ah, bl, acc0, 0, 0, 0);
        acc0 = __builtin_amdgcn_mfma_f32_16x16x32_bf16(al, bh, acc0, 0, 0, 0);
    }

    // epilogue: bias + ELU + store xout; D layout col=lane&15, row=(lane>>4)*4+reg
    float ev2[4];
    {
        int c = wid * 16 + arow;
        float bc = bg[c];
        #pragma unroll
        for (int r = 0; r < 4; r++) {
            int node = nb + kg * 4 + r;
            float v = acc0[r] * 0.25f + bc;
            float e = v > 0.f ? v : expm1f(v);
            ev2[r] = e;
            if (node < NNODE)
                xout[((size_t)g * NNODE + node) * HID + c] = e;
        }
    }
    if (wa4) {
        float* s_part = &s_e[0][0][0];    // [4][16][8] floats = 512, s_e dead after GEMM barrier
        #pragma unroll
        for (int r = 0; r < 4; r++) {
            float4 pls = make_float4(0.f, 0.f, 0.f, 0.f);
            float4 pld = make_float4(0.f, 0.f, 0.f, 0.f);
            {
                int c = wid * 16 + arow;
                float e = ev2[r];
                float4 wa_c = wa4[c];
                float4 wd_c = wd4[c];
                pls.x += e * wa_c.x; pls.y += e * wa_c.y;
                pls.z += e * wa_c.z; pls.w += e * wa_c.w;
                pld.x += e * wd_c.x; pld.y += e * wd_c.y;
                pld.z += e * wd_c.z; pld.w += e * wd_c.w;
            }
            #pragma unroll
            for (int o = 1; o < 16; o <<= 1) {
                pls.x += __shfl_xor(pls.x, o, 64); pls.y += __shfl_xor(pls.y, o, 64);
                pls.z += __shfl_xor(pls.z, o, 64); pls.w += __shfl_xor(pls.w, o, 64);
                pld.x += __shfl_xor(pld.x, o, 64); pld.y += __shfl_xor(pld.y, o, 64);
                pld.z += __shfl_xor(pld.z, o, 64); pld.w += __shfl_xor(pld.w, o, 64);
            }
            if (arow == 0) {
                int rl = kg * 4 + r;
                float4* p = reinterpret_cast<float4*>(&s_part[(wid * 16 + rl) * 8]);
                p[0] = pls; p[1] = pld;
            }
        }
        __syncthreads();
        if (tid < 128) {
            int rl = tid >> 3, cc = tid & 7;  // 16 rows x 8 components
            int node = nb + rl;
            if (node < NNODE) {
                float v = s_part[(0 * 16 + rl) * 8 + cc] + s_part[(1 * 16 + rl) * 8 + cc]
                        + s_part[(2 * 16 + rl) * 8 + cc] + s_part[(3 * 16 + rl) * 8 + cc];
                float* dst = (cc < 4) ? reinterpret_cast<float*>(lso4) : reinterpret_cast<float*>(ldo4);
                dst[((size_t)g * NNODE + node) * 4 + (cc & 3)] = v;
            }
        }
    }
}

// ---------------- GRU input GEMM: 500 K-slices, full 64x192 tile/block, no atomics ----------------
__global__ __launch_bounds__(256) void k_gi_gemm(const float* __restrict__ x, const float* __restrict__ W_ih,
                                                 float* __restrict__ gip) {
    __shared__ float xs[32 * 68];    // [kk][row], pitch 68
    __shared__ float ws[32 * 196];   // [kk][col 0..191], pitch 196
    int k0 = blockIdx.x * GIK;
    int tid = threadIdx.x;
    int lane = tid & 63;
    int wv = tid >> 6;
    int tx = tid & 15, ty = tid >> 4;
    float4 accs[4][3];
    #pragma unroll
    for (int i = 0; i < 4; i++)
        #pragma unroll
        for (int j = 0; j < 3; j++) accs[i][j] = make_float4(0.f, 0.f, 0.f, 0.f);

    for (int kt = 0; kt < GIK / 32; kt++) {
        int kb = k0 + kt * 32;
        #pragma unroll
        for (int it = 0; it < 2; it++) {
            int kq = wv + 4 * it;
            float4 v = *reinterpret_cast<const float4*>(&x[(size_t)lane * KGI + kb + kq * 4]);
            int k = kq * 4;
            xs[(k + 0) * 68 + lane] = v.x;
            xs[(k + 1) * 68 + lane] = v.y;
            xs[(k + 2) * 68 + lane] = v.z;
            xs[(k + 3) * 68 + lane] = v.w;
        }
        #pragma unroll
        for (int cg = 0; cg < 3; cg++) {
            #pragma unroll
            for (int it = 0; it < 2; it++) {
                int kq = wv + 4 * it;
                int c = cg * 64 + lane;
                float4 v = *reinterpret_cast<const float4*>(&W_ih[(size_t)c * KGI + kb + kq * 4]);
                int k = kq * 4;
                ws[(k + 0) * 196 + c] = v.x;
                ws[(k + 1) * 196 + c] = v.y;
                ws[(k + 2) * 196 + c] = v.z;
                ws[(k + 3) * 196 + c] = v.w;
            }
        }
        __syncthreads();
        for (int kk = 0; kk < 32; kk++) {
            float4 xv = *reinterpret_cast<const float4*>(&xs[kk * 68 + ty * 4]);
            float4 w0 = *reinterpret_cast<const float4*>(&ws[kk * 196 + tx * 4]);
            float4 w1 = *reinterpret_cast<const float4*>(&ws[kk * 196 + 64 + tx * 4]);
            float4 w2 = *reinterpret_cast<const float4*>(&ws[kk * 196 + 128 + tx * 4]);
            #pragma unroll
            for (int i = 0; i < 4; i++) {
                float xi = (i == 0) ? xv.x : (i == 1) ? xv.y : (i == 2) ? xv.z : xv.w;
                accs[i][0].x += xi * w0.x; accs[i][0].y += xi * w0.y; accs[i][0].z += xi * w0.z; accs[i][0].w += xi * w0.w;
                accs[i][1].x += xi * w1.x; accs[i][1].y += xi * w1.y; accs[i][1].z += xi * w1.z; accs[i][1].w += xi * w1.w;
                accs[i][2].x += xi * w2.x; accs[i][2].y += xi * w2.y; accs[i][2].z += xi * w2.z; accs[i][2].w += xi * w2.w;
            }
        }
        __syncthreads();
    }
    float* out = gip + (size_t)blockIdx.x * GOSZ;
    #pragma unroll
    for (int i = 0; i < 4; i++)
        #pragma unroll
        for (int j = 0; j < 3; j++)
            *reinterpret_cast<float4*>(&out[(ty * 4 + i) * GOUT + j * 64 + tx * 4]) = accs[i][j];
}

__global__ void k_gi_reduce1(const float* __restrict__ gip, float* __restrict__ gip2) {
    int idx = blockIdx.x * 256 + threadIdx.x;     // 0..GOSZ-1
    const float* p = gip + (size_t)blockIdx.y * 50 * GOSZ + idx;
    float a = 0.f;
    #pragma unroll 5
    for (int s = 0; s < 50; s++) a += p[(size_t)s * GOSZ];
    gip2[blockIdx.y * GOSZ + idx] = a;
}

__global__ void k_gi_reduce2(const float* __restrict__ gip2, const float* __restrict__ b_ih,
                             float* __restrict__ gi) {
    int idx = blockIdx.x * 256 + threadIdx.x;
    float a = b_ih[idx % GOUT];
    #pragma unroll
    for (int y = 0; y < 10; y++) a += gip2[(size_t)y * GOSZ + idx];
    gi[idx] = a;
}

// ---------------- GRU scan: one block per batch, W_hh row in registers, LDS broadcast hs ----------------
__global__ __launch_bounds__(192) void k_gru(const float* __restrict__ gi, const float* __restrict__ W_hh,
                                             const float* __restrict__ b_hh, float* __restrict__ hT) {
    __shared__ float hs[64];
    __shared__ float gh[192];
    int j = threadIdx.x;      // 0..191
    int b = blockIdx.x;       // 0..3
    float wrow[64];
    #pragma unroll
    for (int q = 0; q < 16; q++) {
        float4 v = *reinterpret_cast<const float4*>(&W_hh[(size_t)j * 64 + q * 4]);
        wrow[q * 4 + 0] = v.x; wrow[q * 4 + 1] = v.y;
        wrow[q * 4 + 2] = v.z; wrow[q * 4 + 3] = v.w;
    }
    float bj = b_hh[j];
    if (j < 64) hs[j] = 0.f;
    __syncthreads();
    for (int t = 0; t < TT; t++) {
        float a0 = 0.f, a1 = 0.f, a2 = 0.f, a3 = 0.f;
        #pragma unroll
        for (int q = 0; q < 16; q++) {
            float4 h4 = *reinterpret_cast<const float4*>(&hs[q * 4]);   // broadcast read
            a0 += h4.x * wrow[q * 4 + 0];
            a1 += h4.y * wrow[q * 4 + 1];
            a2 += h4.z * wrow[q * 4 + 2];
            a3 += h4.w * wrow[q * 4 + 3];
        }
        gh[j] = bj + ((a0 + a1) + (a2 + a3));
        __syncthreads();
        if (j < 64) {
            int row = (b * TT + t) * GOUT;
            float ir = gi[row + j], iz = gi[row + 64 + j], in_ = gi[row + 128 + j];
            float r = 1.f / (1.f + expf(-(ir + gh[j])));
            float z = 1.f / (1.f + expf(-(iz + gh[64 + j])));
            float nv = tanhf(in_ + r * gh[128 + j]);
            hs[j] = (1.f - z) * nv + z * hs[j];
        }
        __syncthreads();
    }
    if (j < 64) hT[b * 64 + j] = hs[j];
}

// ---------------- final FC ----------------
__global__ void k_final(const float* __restrict__ hT, const float* __restrict__ W_fc,
                        const float* __restrict__ b_fc, float* __restrict__ out) {
    int idx = blockIdx.x * 256 + threadIdx.x;
    if (idx >= NB * NNODE) return;
    int b = idx / NNODE, n = idx % NNODE;
    float acc = b_fc[n];
    #pragma unroll
    for (int c = 0; c < HID; c++) acc += hT[b * HID + c] * W_fc[c * NNODE + n];
    out[idx] = acc;
}

extern "C" void kernel_launch(void* const* d_in, const int* in_sizes, int n_in,
                              void* d_out, int out_size, void* d_ws, size_t ws_size,
                              hipStream_t stream) {
    const float* x_seq  = (const float*)d_in[0];
    const int*   eidx   = (const int*)  d_in[1];
    // d_in[2] edge_weight: unused by GATConv
    const float* W_in   = (const float*)d_in[3];
    const float* b_in   = (const float*)d_in[4];
    const float* Wg     = (const float*)d_in[5];
    const float* a_src  = (const float*)d_in[6];
    const float* a_dst  = (const float*)d_in[7];
    const float* bg     = (const float*)d_in[8];
    const float* W_ih   = (const float*)d_in[9];
    const float* W_hh   = (const float*)d_in[10];
    const float* b_ih   = (const float*)d_in[11];
    const float* b_hh   = (const float*)d_in[12];
    const float* W_fc   = (const float*)d_in[13];
    const float* b_fc   = (const float*)d_in[14];
    float* out = (float*)d_out;

    float* wsf = (float*)d_ws;
    size_t off = 0;
    float* x0a    = wsf + off; off += (size_t)ROWS * HID;       // 4,096,000 floats
    float* x0b    = wsf + off; off += (size_t)ROWS * HID;       // 4,096,000
    float* lsa    = wsf + off; off += (size_t)ROWS * HEADS;     // 256,000
    float* ldaf   = wsf + off; off += (size_t)ROWS * HEADS;
    float* lsbf   = wsf + off; off += (size_t)ROWS * HEADS;
    float* ldbf   = wsf + off; off += (size_t)ROWS * HEADS;
    float* wab    = wsf + off; off += NL * HCOL;                // 1,280
    float* wdb    = wsf + off; off += NL * HCOL;
    float* gib    = wsf + off; off += GOSZ;                     // 12,288
    float* hTb    = wsf + off; off += 256;
    u16* wphb     = (u16*)(wsf + off); off += NL * WPSZ / 2;    // 40,960 floats
    u16* wplb     = (u16*)(wsf + off); off += NL * WPSZ / 2;
    float* gip    = wsf + off; off += (size_t)KSPLIT * GOSZ;    // 6,144,000
    float* gip2   = wsf + off; off += 10 * GOSZ;                // 122,880
    int* ib = (int*)(wsf + off);
    int* src_e    = ib;          ib += EP;
    int* dst_e    = ib;          ib += EP;
    int* rowptr_p = ib;          ib += NNODE + 1;
    int* csr_src  = ib;          ib += EPAD;
    int* deg      = ib;          ib += NNODE;
    int* fill     = ib;          ib += NNODE;

    k_build_edges<<<(EP + 255) / 256, 256, 0, stream>>>(eidx, src_e, dst_e, deg, fill);
    k_csr_count<<<(EP + 255) / 256, 256, 0, stream>>>(dst_e, deg);
    k_csr_scan<<<1, 256, 0, stream>>>(deg, rowptr_p);
    k_csr_fill<<<(EP + 255) / 256, 256, 0, stream>>>(src_e, dst_e, rowptr_p, deg, fill, csr_src);

    k_wa<<<10, 256, 0, stream>>>(Wg, a_src, a_dst, wab, wdb);
    k_wpack<<<(NL * WPSZ + 255) / 256, 256, 0, stream>>>(Wg, wphb, wplb);

    k_input_fc<<<ROWS * 16 / 256, 256, 0, stream>>>(
        x_seq, (const float4*)W_in, (const float4*)b_in,
        (const float4*)wab, (const float4*)wdb, (float4*)x0a, (float4*)lsa, (float4*)ldaf);

    float* xc = x0a;  float* xn = x0b;
    float* lsc = lsa; float* ldc = ldaf;
    float* lsn = lsbf; float* ldn = ldbf;
    for (int l = 0; l < NL; l++) {
        const float4* wa_next = (l + 1 < NL) ? (const float4*)(wab + (size_t)(l + 1) * HCOL) : nullptr;
        const float4* wd_next = (l + 1 < NL) ? (const float4*)(wdb + (size_t)(l + 1) * HCOL) : nullptr;
        k_gat_fused<<<GG * NBLK, 256, 0, stream>>>(
            (const float4*)xc, (const float4*)lsc, (const float4*)ldc,
            rowptr_p, csr_src, deg,
            wphb + (size_t)l * WPSZ, wplb + (size_t)l * WPSZ, bg + (size_t)l * HID,
            xn, wa_next, wd_next, (float4*)lsn, (float4*)ldn);
        float* t;
        t = xc; xc = xn; xn = t;
        t = lsc; lsc = lsn; lsn = t;
        t = ldc; ldc = ldn; ldn = t;
    }

    k_gi_gemm<<<KSPLIT, 256, 0, stream>>>(xc, W_ih, gip);
    k_gi_reduce1<<<dim3(GOSZ / 256, 10), 256, 0, stream>>>(gip, gip2);
    k_gi_reduce2<<<GOSZ / 256, 256, 0, stream>>>(gip2, b_ih, gib);
    k_gru<<<4, 192, 0, stream>>>(gib, W_hh, b_hh, hTb);
    k_final<<<(NB * NNODE + 255) / 256, 256, 0, stream>>>(hTb, W_fc, b_fc, out);
}

// Round 19
// 414.644 us; speedup vs baseline: 1.0080x; 1.0080x over previous
//
#include <hip/hip_runtime.h>
#include <math.h>

#define NB 4
#define TT 16
#define NNODE 1000
#define FIN 8
#define EE 8000
#define EP 9000          // E + N self loops
#define EPAD 16384       // max padded edges (pad rows to mult of 8)
#define HID 64
#define HEADS 4
#define NL 5
#define GG (NB*TT)       // 64 graphs
#define ROWS (GG*NNODE)  // 64000
#define HCOL (HEADS*HID) // 256
#define KGI (NNODE*HID)  // 64000
#define GOUT 192         // 3*HID
#define GIK 128          // K-slice per gi-gemm block
#define KSPLIT (KGI/GIK) // 500 partial slabs
#define GOSZ (GG*GOUT)   // 12288
#define WPSZ (8*4*64*8)  // 16384 packed W elems per layer

typedef unsigned short u16;
typedef __attribute__((ext_vector_type(8))) short short8;
typedef __attribute__((ext_vector_type(4))) float f32x4;

__device__ inline u16 f2bf(float f) {
    unsigned int u = __float_as_uint(f);
    unsigned int r = u + 0x7FFFu + ((u >> 16) & 1u);   // RNE
    return (u16)(r >> 16);
}
__device__ inline float bf2f(u16 h) {
    return __uint_as_float(((unsigned int)h) << 16);
}
__device__ inline ushort4 bfhi4(float4 a) {
    ushort4 r; r.x = f2bf(a.x); r.y = f2bf(a.y); r.z = f2bf(a.z); r.w = f2bf(a.w); return r;
}
__device__ inline ushort4 bflo4(float4 a, ushort4 h) {
    ushort4 r;
    r.x = f2bf(a.x - bf2f(h.x)); r.y = f2bf(a.y - bf2f(h.y));
    r.z = f2bf(a.z - bf2f(h.z)); r.w = f2bf(a.w - bf2f(h.w));
    return r;
}

// ---------------- edge prep ----------------
__global__ void k_build_edges(const int* __restrict__ eidx, int* __restrict__ src_e,
                              int* __restrict__ dst_e, int* __restrict__ deg, int* __restrict__ fill) {
    int i = blockIdx.x * blockDim.x + threadIdx.x;
    if (i < EP) {
        int s, d;
        if (i < EE) { s = eidx[i]; d = eidx[EE + i]; }
        else { s = i - EE; d = i - EE; }
        src_e[i] = s; dst_e[i] = d;
    }
    if (i < NNODE) { deg[i] = 0; fill[i] = 0; }
}

__global__ void k_csr_count(const int* __restrict__ dst_e, int* __restrict__ deg) {
    int i = blockIdx.x * blockDim.x + threadIdx.x;
    if (i < EP) atomicAdd(&deg[dst_e[i]], 1);
}

// parallel inclusive scan of PADDED degrees (pad to multiple of 8)
__global__ __launch_bounds__(256) void k_csr_scan(const int* __restrict__ deg, int* __restrict__ rowptr_p) {
    __shared__ int s[1024];
    int tid = threadIdx.x;
    for (int i = tid; i < 1024; i += 256) s[i] = (i < NNODE) ? ((deg[i] + 7) & ~7) : 0;
    __syncthreads();
    for (int off = 1; off < 1024; off <<= 1) {
        int t[4];
        #pragma unroll
        for (int q = 0; q < 4; q++) { int i = tid + 256 * q; t[q] = (i >= off) ? s[i - off] : 0; }
        __syncthreads();
        #pragma unroll
        for (int q = 0; q < 4; q++) { int i = tid + 256 * q; s[i] += t[q]; }
        __syncthreads();
    }
    for (int i = tid; i < NNODE; i += 256) rowptr_p[i + 1] = s[i];
    if (tid == 0) rowptr_p[0] = 0;
}

// fill CSR + pad slots (disjoint writes; pad needs only rowptr_p/deg, no ordering vs fill)
__global__ void k_csr_fill(const int* __restrict__ src_e, const int* __restrict__ dst_e,
                           const int* __restrict__ rowptr_p, const int* __restrict__ deg,
                           int* __restrict__ fill, int* __restrict__ csr_src) {
    int i = blockIdx.x * blockDim.x + threadIdx.x;
    if (i < EP) {
        int d = dst_e[i];
        int pos = atomicAdd(&fill[d], 1);
        csr_src[rowptr_p[d] + pos] = src_e[i];
    }
    if (i < NNODE) {
        int rs = rowptr_p[i], re = rowptr_p[i + 1];
        for (int j = rs + deg[i]; j < re; j++) csr_src[j] = i;
    }
}

// ---------------- precompute wa/wd: wa[l][j][h] = sum_c W_l[j, h*64+c] * a_src[l,h,c] ----------------
__global__ void k_wa(const float* __restrict__ Wg, const float* __restrict__ a_src,
                     const float* __restrict__ a_dst, float* __restrict__ wa, float* __restrict__ wd) {
    int t = blockIdx.x * 256 + threadIdx.x;      // 2*NL*HID*HEADS = 2560
    if (t >= 2 * NL * HID * HEADS) return;
    int kind = t >= NL * HID * HEADS;
    int u = t - kind * NL * HID * HEADS;
    int l = u >> 8;
    int rem = u & 255;
    int j = rem >> 2, hd = rem & 3;
    const float* a = (kind ? a_dst : a_src) + (size_t)l * HCOL + hd * HID;
    const float* Wl = Wg + (size_t)l * HID * HCOL + (size_t)j * HCOL + hd * HID;
    float acc = 0.f;
    #pragma unroll 8
    for (int c = 0; c < HID; c++) acc += Wl[c] * a[c];
    float* out = kind ? wd : wa;
    out[(size_t)l * HCOL + j * 4 + hd] = acc;
}

// ---------------- pack W into MFMA B-frag order, split bf16 hi/lo ----------------
// B frag layout (16x16x32): lane needs B[k=(lane>>4)*8+j][col=lane&15]
// wp[((l*8+ks)*4+ct)*512 + lane*8 + j] = W'[ks*32+(lane>>4)*8+j][ct*16+(lane&15)]
// where W'[k][c'] = Wg[l][k&63][(k>>6)*64+c']
__global__ void k_wpack(const float* __restrict__ Wg, u16* __restrict__ wph, u16* __restrict__ wpl) {
    int t = blockIdx.x * 256 + threadIdx.x;      // NL*WPSZ = 81920
    if (t >= NL * WPSZ) return;
    int j    = t & 7;
    int lane = (t >> 3) & 63;
    int ct   = (t >> 9) & 3;
    int ks   = (t >> 11) & 7;
    int l    = t >> 14;
    int k = ks * 32 + (lane >> 4) * 8 + j;
    int c = ct * 16 + (lane & 15);
    float v = Wg[(size_t)l * HID * HCOL + (size_t)(k & 63) * HCOL + (k >> 6) * 64 + c];
    u16 h = f2bf(v);
    wph[t] = h;
    wpl[t] = f2bf(v - bf2f(h));
}

// ---------------- input projection + fused layer-0 ls/ld ----------------
__global__ void k_input_fc(const float* __restrict__ xseq, const float4* __restrict__ Win4,
                           const float4* __restrict__ b_in4, const float4* __restrict__ wa04,
                           const float4* __restrict__ wd04, float4* __restrict__ x0,
                           float4* __restrict__ ls4, float4* __restrict__ ld4) {
    int idx = blockIdx.x * 256 + threadIdx.x;   // ROWS*16 threads
    int r = idx >> 4, c4 = idx & 15;
    float4 acc = b_in4[c4];
    #pragma unroll
    for (int k = 0; k < FIN; k++) {
        float xv = xseq[r * FIN + k];
        float4 w = Win4[k * 16 + c4];
        acc.x += xv * w.x; acc.y += xv * w.y; acc.z += xv * w.z; acc.w += xv * w.w;
    }
    x0[idx] = acc;
    float xr[4] = {acc.x, acc.y, acc.z, acc.w};
    float4 pls = make_float4(0.f, 0.f, 0.f, 0.f);
    float4 pld = make_float4(0.f, 0.f, 0.f, 0.f);
    #pragma unroll
    for (int jj = 0; jj < 4; jj++) {
        float4 wa_j = wa04[c4 * 4 + jj];
        float4 wd_j = wd04[c4 * 4 + jj];
        pls.x += xr[jj] * wa_j.x; pls.y += xr[jj] * wa_j.y;
        pls.z += xr[jj] * wa_j.z; pls.w += xr[jj] * wa_j.w;
        pld.x += xr[jj] * wd_j.x; pld.y += xr[jj] * wd_j.y;
        pld.z += xr[jj] * wd_j.z; pld.w += xr[jj] * wd_j.w;
    }
    #pragma unroll
    for (int o = 1; o < 16; o <<= 1) {
        pls.x += __shfl_xor(pls.x, o, 64); pls.y += __shfl_xor(pls.y, o, 64);
        pls.z += __shfl_xor(pls.z, o, 64); pls.w += __shfl_xor(pls.w, o, 64);
        pld.x += __shfl_xor(pld.x, o, 64); pld.y += __shfl_xor(pld.y, o, 64);
        pld.z += __shfl_xor(pld.z, o, 64); pld.w += __shfl_xor(pld.w, o, 64);
    }
    if (c4 == 0) {
        ls4[r] = pls;
        ld4[r] = pld;
    }
}

// ---------------- FUSED GAT layer: softmax+aggregate (y in LDS) -> MFMA GEMM -> ELU + next ls/ld ----
// Block = 256 thr, 32 nodes of one graph. Grid = 64 graphs x 32 blocks = 2048 (nodes 1000..1023 invalid).
// Agg: 4 waves x 4 nodes x 2 iters -> y tile (bf16 hi/lo) in LDS [32][264].
// BARRIERS inside it2 loop: the loop creates a cross-iteration WAR hazard on s_e/s_src (iteration 1's
// writes vs iteration 0's cross-lane gather reads) that the single-shot unfused kernel never had.
// GEMM: wave = 16 rows x 32 cols (2 ct tiles), A from LDS, B = packed W (L2). 3-term split-bf16.
// NOTE: reads layer-l state (x4/ls4/ld4), writes layer-(l+1) state -> MUST ping-pong buffers.
__global__ __launch_bounds__(256) void k_gat_fused(
        const float4* __restrict__ x4, const float4* __restrict__ ls4, const float4* __restrict__ ld4,
        const int* __restrict__ rowptr_p, const int* __restrict__ csr_src, const int* __restrict__ deg,
        const u16* __restrict__ wph, const u16* __restrict__ wpl, const float* __restrict__ bg,
        float* __restrict__ xout, const float4* __restrict__ wa4, const float4* __restrict__ wd4,
        float4* __restrict__ lso4, float4* __restrict__ ldo4) {
    __shared__ u16 yhs[32][264];          // 16.5 KB
    __shared__ u16 yls[32][264];          // 16.5 KB
    __shared__ float s_e[4][4][264];      // 16.9 KB (aliased as ls/ld partials in epilogue)
    __shared__ unsigned short s_src[4][4][64];  // 2 KB
    __shared__ float s_den[4][4][4];
    int b = blockIdx.x;
    int xcd = b & 7, sb = b >> 3;         // XCD round-robin: graph's 32 blocks on one XCD
    int g = xcd + 8 * (sb >> 5);          // graph 0..63
    int nb = (sb & 31) * 32;              // node base within graph
    int tid = threadIdx.x;
    int wid = tid >> 6, lane = tid & 63;
    int nsub = lane >> 4;                 // node slot 0..3
    int j0 = lane & 15;
    int c4 = lane & 15;
    const float4* lsg = ls4 + (size_t)g * NNODE;
    const float4* xg = x4 + (size_t)g * NNODE * 16 + c4;

    // ---------- aggregation phase: 2 iterations of 4 nodes per wave ----------
    for (int it2 = 0; it2 < 2; it2++) {
        __syncthreads();                  // protect prior iteration's s_e/s_src reads from this iter's writes
        int n_l = wid * 8 + it2 * 4 + nsub;   // local row 0..31
        int n_s = nb + n_l;                   // node in graph
        int valid = n_s < NNODE;
        int n_c = valid ? n_s : (NNODE - 1);  // clamped address
        int rs = rowptr_p[n_c];
        int dgp = valid ? (rowptr_p[n_c + 1] - rs) : 0;
        int dg = valid ? deg[n_c] : 0;
        int dg16 = (dgp + 15) & ~15;
        if (dg16 > 64) dg16 = 64;
        if (dgp > 64) dgp = 64;
        if (dg > 64) dg = 64;
        float4 ldv = ld4[(size_t)g * NNODE + n_c];

        // pass A: logits + running max (4-head float4 at s_e[..][j*4])
        float4 mx = make_float4(-1e30f, -1e30f, -1e30f, -1e30f);
        for (int base = 0; base < dg16; base += 16) {
            int j = base + j0;
            int sv = n_c;
            if (j < dgp) sv = csr_src[rs + j];
            s_src[wid][nsub][j] = (unsigned short)sv;
            float4 lo = make_float4(-1e30f, -1e30f, -1e30f, -1e30f);
            if (j < dg) {
                float4 t = lsg[sv];
                t.x += ldv.x; t.y += ldv.y; t.z += ldv.z; t.w += ldv.w;
                t.x = fmaxf(t.x, 0.2f * t.x); t.y = fmaxf(t.y, 0.2f * t.y);
                t.z = fmaxf(t.z, 0.2f * t.z); t.w = fmaxf(t.w, 0.2f * t.w);
                lo = t;
                mx.x = fmaxf(mx.x, lo.x); mx.y = fmaxf(mx.y, lo.y);
                mx.z = fmaxf(mx.z, lo.z); mx.w = fmaxf(mx.w, lo.w);
            }
            *reinterpret_cast<float4*>(&s_e[wid][nsub][j * 4]) = lo;
        }
        #pragma unroll
        for (int o = 1; o < 16; o <<= 1) {
            mx.x = fmaxf(mx.x, __shfl_xor(mx.x, o, 64));
            mx.y = fmaxf(mx.y, __shfl_xor(mx.y, o, 64));
            mx.z = fmaxf(mx.z, __shfl_xor(mx.z, o, 64));
            mx.w = fmaxf(mx.w, __shfl_xor(mx.w, o, 64));
        }
        // pass B: exp + denominator
        float4 den = make_float4(0.f, 0.f, 0.f, 0.f);
        for (int base = 0; base < dg16; base += 16) {
            int j = base + j0;
            float4 e = make_float4(0.f, 0.f, 0.f, 0.f);
            if (j < dg) {
                float4 lo = *reinterpret_cast<const float4*>(&s_e[wid][nsub][j * 4]);
                e.x = __expf(lo.x - mx.x);
                e.y = __expf(lo.y - mx.y);
                e.z = __expf(lo.z - mx.z);
                e.w = __expf(lo.w - mx.w);
            }
            den.x += e.x; den.y += e.y; den.z += e.z; den.w += e.w;
            *reinterpret_cast<float4*>(&s_e[wid][nsub][j * 4]) = e;
        }
        #pragma unroll
        for (int o = 1; o < 16; o <<= 1) {
            den.x += __shfl_xor(den.x, o, 64);
            den.y += __shfl_xor(den.y, o, 64);
            den.z += __shfl_xor(den.z, o, 64);
            den.w += __shfl_xor(den.w, o, 64);
        }
        if (j0 == 0) *reinterpret_cast<float4*>(&s_den[wid][nsub][0]) = den;
        __syncthreads();                  // all s_e/s_den/s_src writes visible before gather

        // gather: lane (nsub,c4) owns one node's col slice, all 4 heads
        float4 a0 = make_float4(0.f, 0.f, 0.f, 0.f);
        float4 a1 = a0, a2 = a0, a3 = a0;
        const float* ep = &s_e[wid][nsub][0];
        const unsigned short* sp = &s_src[wid][nsub][0];
        int dg4 = (dg + 3) & ~3;
        int q = 0;
        for (; q + 8 <= dg4; q += 8) {
            int sj[8]; float4 ev[8], xv[8];
            #pragma unroll
            for (int u = 0; u < 8; u++) sj[u] = sp[q + u];
            #pragma unroll
            for (int u = 0; u < 8; u++) xv[u] = xg[(size_t)sj[u] * 16];
            #pragma unroll
            for (int u = 0; u < 8; u++) ev[u] = *reinterpret_cast<const float4*>(&ep[(q + u) * 4]);
            #pragma unroll
            for (int u = 0; u < 8; u++) {
                a0.x += ev[u].x * xv[u].x; a0.y += ev[u].x * xv[u].y;
                a0.z += ev[u].x * xv[u].z; a0.w += ev[u].x * xv[u].w;
                a1.x += ev[u].y * xv[u].x; a1.y += ev[u].y * xv[u].y;
                a1.z += ev[u].y * xv[u].z; a1.w += ev[u].y * xv[u].w;
                a2.x += ev[u].z * xv[u].x; a2.y += ev[u].z * xv[u].y;
                a2.z += ev[u].z * xv[u].z; a2.w += ev[u].z * xv[u].w;
                a3.x += ev[u].w * xv[u].x; a3.y += ev[u].w * xv[u].y;
                a3.z += ev[u].w * xv[u].z; a3.w += ev[u].w * xv[u].w;
            }
        }
        if (q < dg4) {
            int sj[4]; float4 ev[4], xv[4];
            #pragma unroll
            for (int u = 0; u < 4; u++) sj[u] = sp[q + u];
            #pragma unroll
            for (int u = 0; u < 4; u++) xv[u] = xg[(size_t)sj[u] * 16];
            #pragma unroll
            for (int u = 0; u < 4; u++) ev[u] = *reinterpret_cast<const float4*>(&ep[(q + u) * 4]);
            #pragma unroll
            for (int u = 0; u < 4; u++) {
                a0.x += ev[u].x * xv[u].x; a0.y += ev[u].x * xv[u].y;
                a0.z += ev[u].x * xv[u].z; a0.w += ev[u].x * xv[u].w;
                a1.x += ev[u].y * xv[u].x; a1.y += ev[u].y * xv[u].y;
                a1.z += ev[u].y * xv[u].z; a1.w += ev[u].y * xv[u].w;
                a2.x += ev[u].z * xv[u].x; a2.y += ev[u].z * xv[u].y;
                a2.z += ev[u].z * xv[u].z; a2.w += ev[u].z * xv[u].w;
                a3.x += ev[u].w * xv[u].x; a3.y += ev[u].w * xv[u].y;
                a3.z += ev[u].w * xv[u].z; a3.w += ev[u].w * xv[u].w;
            }
        }
        float4 dv = *reinterpret_cast<const float4*>(&s_den[wid][nsub][0]);
        float i0 = 1.f / (dv.x + 1e-16f), i1 = 1.f / (dv.y + 1e-16f);
        float i2 = 1.f / (dv.z + 1e-16f), i3 = 1.f / (dv.w + 1e-16f);
        a0.x *= i0; a0.y *= i0; a0.z *= i0; a0.w *= i0;
        a1.x *= i1; a1.y *= i1; a1.z *= i1; a1.w *= i1;
        a2.x *= i2; a2.y *= i2; a2.z *= i2; a2.w *= i2;
        a3.x *= i3; a3.y *= i3; a3.z *= i3; a3.w *= i3;
        ushort4 h0 = bfhi4(a0), h1 = bfhi4(a1), h2 = bfhi4(a2), h3 = bfhi4(a3);
        *reinterpret_cast<ushort4*>(&yhs[n_l][0 * 64 + c4 * 4]) = h0;
        *reinterpret_cast<ushort4*>(&yhs[n_l][1 * 64 + c4 * 4]) = h1;
        *reinterpret_cast<ushort4*>(&yhs[n_l][2 * 64 + c4 * 4]) = h2;
        *reinterpret_cast<ushort4*>(&yhs[n_l][3 * 64 + c4 * 4]) = h3;
        *reinterpret_cast<ushort4*>(&yls[n_l][0 * 64 + c4 * 4]) = bflo4(a0, h0);
        *reinterpret_cast<ushort4*>(&yls[n_l][1 * 64 + c4 * 4]) = bflo4(a1, h1);
        *reinterpret_cast<ushort4*>(&yls[n_l][2 * 64 + c4 * 4]) = bflo4(a2, h2);
        *reinterpret_cast<ushort4*>(&yls[n_l][3 * 64 + c4 * 4]) = bflo4(a3, h3);
    }
    __syncthreads();

    // ---------- GEMM phase: wave = rows (wid&1)*16..+16, cols (wid>>1)*32..+32 ----------
    int r0l = (wid & 1) * 16;
    int ch = wid >> 1;
    int arow = lane & 15, kg = lane >> 4;
    f32x4 acc0 = {0.f, 0.f, 0.f, 0.f};
    f32x4 acc1 = {0.f, 0.f, 0.f, 0.f};
    const short8* bh8 = reinterpret_cast<const short8*>(wph) + lane;
    const short8* bl8 = reinterpret_cast<const short8*>(wpl) + lane;
    #pragma unroll
    for (int ks = 0; ks < 8; ks++) {
        short8 ah = *reinterpret_cast<const short8*>(&yhs[r0l + arow][ks * 32 + kg * 8]);
        short8 al = *reinterpret_cast<const short8*>(&yls[r0l + arow][ks * 32 + kg * 8]);
        #pragma unroll
        for (int ctl = 0; ctl < 2; ctl++) {
            int ctg = ch * 2 + ctl;
            short8 bh = bh8[(size_t)(ks * 4 + ctg) * 64];
            short8 bl = bl8[(size_t)(ks * 4 + ctg) * 64];
            f32x4* ac = ctl ? &acc1 : &acc0;
            *ac = __builtin_amdgcn_mfma_f32_16x16x32_bf16(ah, bh, *ac, 0, 0, 0);
            *ac = __builtin_amdgcn_mfma_f32_16x16x32_bf16(ah, bl, *ac, 0, 0, 0);
            *ac = __builtin_amdgcn_mfma_f32_16x16x32_bf16(al, bh, *ac, 0, 0, 0);
        }
    }

    // epilogue: bias + ELU + store xout; D layout col=lane&15, row=(lane>>4)*4+reg
    float ev2[2][4];
    #pragma unroll
    for (int ctl = 0; ctl < 2; ctl++) {
        int c = (ch * 2 + ctl) * 16 + arow;
        float bc = bg[c];
        f32x4 a = ctl ? acc1 : acc0;
        #pragma unroll
        for (int r = 0; r < 4; r++) {
            int node = nb + r0l + kg * 4 + r;
            float v = a[r] * 0.25f + bc;
            float e = v > 0.f ? v : expm1f(v);
            ev2[ctl][r] = e;
            if (node < NNODE)
                xout[((size_t)g * NNODE + node) * HID + c] = e;
        }
    }
    if (wa4) {
        float* s_part = &s_e[0][0][0];    // [2][32][8] floats, s_e dead after barrier above
        __syncthreads();                  // ensure all waves done with s_e (gather) before aliasing
        #pragma unroll
        for (int r = 0; r < 4; r++) {
            float4 pls = make_float4(0.f, 0.f, 0.f, 0.f);
            float4 pld = make_float4(0.f, 0.f, 0.f, 0.f);
            #pragma unroll
            for (int ctl = 0; ctl < 2; ctl++) {
                int c = (ch * 2 + ctl) * 16 + arow;
                float e = ev2[ctl][r];
                float4 wa_c = wa4[c];
                float4 wd_c = wd4[c];
                pls.x += e * wa_c.x; pls.y += e * wa_c.y;
                pls.z += e * wa_c.z; pls.w += e * wa_c.w;
                pld.x += e * wd_c.x; pld.y += e * wd_c.y;
                pld.z += e * wd_c.z; pld.w += e * wd_c.w;
            }
            #pragma unroll
            for (int o = 1; o < 16; o <<= 1) {
                pls.x += __shfl_xor(pls.x, o, 64); pls.y += __shfl_xor(pls.y, o, 64);
                pls.z += __shfl_xor(pls.z, o, 64); pls.w += __shfl_xor(pls.w, o, 64);
                pld.x += __shfl_xor(pld.x, o, 64); pld.y += __shfl_xor(pld.y, o, 64);
                pld.z += __shfl_xor(pld.z, o, 64); pld.w += __shfl_xor(pld.w, o, 64);
            }
            if (arow == 0) {
                int rl = r0l + kg * 4 + r;
                float4* p = reinterpret_cast<float4*>(&s_part[(ch * 32 + rl) * 8]);
                p[0] = pls; p[1] = pld;
            }
        }
        __syncthreads();
        int rl = tid >> 3, cc = tid & 7;  // 32 rows x 8 components
        int node = nb + rl;
        if (node < NNODE) {
            float v = s_part[rl * 8 + cc] + s_part[(32 + rl) * 8 + cc];
            float* dst = (cc < 4) ? reinterpret_cast<float*>(lso4) : reinterpret_cast<float*>(ldo4);
            dst[((size_t)g * NNODE + node) * 4 + (cc & 3)] = v;
        }
    }
}

// ---------------- GRU input GEMM: 500 K-slices, full 64x192 tile/block, no atomics ----------------
__global__ __launch_bounds__(256) void k_gi_gemm(const float* __restrict__ x, const float* __restrict__ W_ih,
                                                 float* __restrict__ gip) {
    __shared__ float xs[32 * 68];    // [kk][row], pitch 68
    __shared__ float ws[32 * 196];   // [kk][col 0..191], pitch 196
    int k0 = blockIdx.x * GIK;
    int tid = threadIdx.x;
    int lane = tid & 63;
    int wv = tid >> 6;
    int tx = tid & 15, ty = tid >> 4;
    float4 accs[4][3];
    #pragma unroll
    for (int i = 0; i < 4; i++)
        #pragma unroll
        for (int j = 0; j < 3; j++) accs[i][j] = make_float4(0.f, 0.f, 0.f, 0.f);

    for (int kt = 0; kt < GIK / 32; kt++) {
        int kb = k0 + kt * 32;
        #pragma unroll
        for (int it = 0; it < 2; it++) {
            int kq = wv + 4 * it;
            float4 v = *reinterpret_cast<const float4*>(&x[(size_t)lane * KGI + kb + kq * 4]);
            int k = kq * 4;
            xs[(k + 0) * 68 + lane] = v.x;
            xs[(k + 1) * 68 + lane] = v.y;
            xs[(k + 2) * 68 + lane] = v.z;
            xs[(k + 3) * 68 + lane] = v.w;
        }
        #pragma unroll
        for (int cg = 0; cg < 3; cg++) {
            #pragma unroll
            for (int it = 0; it < 2; it++) {
                int kq = wv + 4 * it;
                int c = cg * 64 + lane;
                float4 v = *reinterpret_cast<const float4*>(&W_ih[(size_t)c * KGI + kb + kq * 4]);
                int k = kq * 4;
                ws[(k + 0) * 196 + c] = v.x;
                ws[(k + 1) * 196 + c] = v.y;
                ws[(k + 2) * 196 + c] = v.z;
                ws[(k + 3) * 196 + c] = v.w;
            }
        }
        __syncthreads();
        for (int kk = 0; kk < 32; kk++) {
            float4 xv = *reinterpret_cast<const float4*>(&xs[kk * 68 + ty * 4]);
            float4 w0 = *reinterpret_cast<const float4*>(&ws[kk * 196 + tx * 4]);
            float4 w1 = *reinterpret_cast<const float4*>(&ws[kk * 196 + 64 + tx * 4]);
            float4 w2 = *reinterpret_cast<const float4*>(&ws[kk * 196 + 128 + tx * 4]);
            #pragma unroll
            for (int i = 0; i < 4; i++) {
                float xi = (i == 0) ? xv.x : (i == 1) ? xv.y : (i == 2) ? xv.z : xv.w;
                accs[i][0].x += xi * w0.x; accs[i][0].y += xi * w0.y; accs[i][0].z += xi * w0.z; accs[i][0].w += xi * w0.w;
                accs[i][1].x += xi * w1.x; accs[i][1].y += xi * w1.y; accs[i][1].z += xi * w1.z; accs[i][1].w += xi * w1.w;
                accs[i][2].x += xi * w2.x; accs[i][2].y += xi * w2.y; accs[i][2].z += xi * w2.z; accs[i][2].w += xi * w2.w;
            }
        }
        __syncthreads();
    }
    float* out = gip + (size_t)blockIdx.x * GOSZ;
    #pragma unroll
    for (int i = 0; i < 4; i++)
        #pragma unroll
        for (int j = 0; j < 3; j++)
            *reinterpret_cast<float4*>(&out[(ty * 4 + i) * GOUT + j * 64 + tx * 4]) = accs[i][j];
}

__global__ void k_gi_reduce1(const float* __restrict__ gip, float* __restrict__ gip2) {
    int idx = blockIdx.x * 256 + threadIdx.x;     // 0..GOSZ-1
    const float* p = gip + (size_t)blockIdx.y * 50 * GOSZ + idx;
    float a = 0.f;
    #pragma unroll 5
    for (int s = 0; s < 50; s++) a += p[(size_t)s * GOSZ];
    gip2[blockIdx.y * GOSZ + idx] = a;
}

__global__ void k_gi_reduce2(const float* __restrict__ gip2, const float* __restrict__ b_ih,
                             float* __restrict__ gi) {
    int idx = blockIdx.x * 256 + threadIdx.x;
    float a = b_ih[idx % GOUT];
    #pragma unroll
    for (int y = 0; y < 10; y++) a += gip2[(size_t)y * GOSZ + idx];
    gi[idx] = a;
}

// ---------------- GRU scan: one block per batch, W_hh row in registers, LDS broadcast hs ----------------
__global__ __launch_bounds__(192) void k_gru(const float* __restrict__ gi, const float* __restrict__ W_hh,
                                             const float* __restrict__ b_hh, float* __restrict__ hT) {
    __shared__ float hs[64];
    __shared__ float gh[192];
    int j = threadIdx.x;      // 0..191
    int b = blockIdx.x;       // 0..3
    float wrow[64];
    #pragma unroll
    for (int q = 0; q < 16; q++) {
        float4 v = *reinterpret_cast<const float4*>(&W_hh[(size_t)j * 64 + q * 4]);
        wrow[q * 4 + 0] = v.x; wrow[q * 4 + 1] = v.y;
        wrow[q * 4 + 2] = v.z; wrow[q * 4 + 3] = v.w;
    }
    float bj = b_hh[j];
    if (j < 64) hs[j] = 0.f;
    __syncthreads();
    for (int t = 0; t < TT; t++) {
        float a0 = 0.f, a1 = 0.f, a2 = 0.f, a3 = 0.f;
        #pragma unroll
        for (int q = 0; q < 16; q++) {
            float4 h4 = *reinterpret_cast<const float4*>(&hs[q * 4]);   // broadcast read
            a0 += h4.x * wrow[q * 4 + 0];
            a1 += h4.y * wrow[q * 4 + 1];
            a2 += h4.z * wrow[q * 4 + 2];
            a3 += h4.w * wrow[q * 4 + 3];
        }
        gh[j] = bj + ((a0 + a1) + (a2 + a3));
        __syncthreads();
        if (j < 64) {
            int row = (b * TT + t) * GOUT;
            float ir = gi[row + j], iz = gi[row + 64 + j], in_ = gi[row + 128 + j];
            float r = 1.f / (1.f + expf(-(ir + gh[j])));
            float z = 1.f / (1.f + expf(-(iz + gh[64 + j])));
            float nv = tanhf(in_ + r * gh[128 + j]);
            hs[j] = (1.f - z) * nv + z * hs[j];
        }
        __syncthreads();
    }
    if (j < 64) hT[b * 64 + j] = hs[j];
}

// ---------------- final FC ----------------
__global__ void k_final(const float* __restrict__ hT, const float* __restrict__ W_fc,
                        const float* __restrict__ b_fc, float* __restrict__ out) {
    int idx = blockIdx.x * 256 + threadIdx.x;
    if (idx >= NB * NNODE) return;
    int b = idx / NNODE, n = idx % NNODE;
    float acc = b_fc[n];
    #pragma unroll
    for (int c = 0; c < HID; c++) acc += hT[b * HID + c] * W_fc[c * NNODE + n];
    out[idx] = acc;
}

extern "C" void kernel_launch(void* const* d_in, const int* in_sizes, int n_in,
                              void* d_out, int out_size, void* d_ws, size_t ws_size,
                              hipStream_t stream) {
    const float* x_seq  = (const float*)d_in[0];
    const int*   eidx   = (const int*)  d_in[1];
    // d_in[2] edge_weight: unused by GATConv
    const float* W_in   = (const float*)d_in[3];
    const float* b_in   = (const float*)d_in[4];
    const float* Wg     = (const float*)d_in[5];
    const float* a_src  = (const float*)d_in[6];
    const float* a_dst  = (const float*)d_in[7];
    const float* bg     = (const float*)d_in[8];
    const float* W_ih   = (const float*)d_in[9];
    const float* W_hh   = (const float*)d_in[10];
    const float* b_ih   = (const float*)d_in[11];
    const float* b_hh   = (const float*)d_in[12];
    const float* W_fc   = (const float*)d_in[13];
    const float* b_fc   = (const float*)d_in[14];
    float* out = (float*)d_out;

    float* wsf = (float*)d_ws;
    size_t off = 0;
    float* x0a    = wsf + off; off += (size_t)ROWS * HID;       // 4,096,000 floats
    float* x0b    = wsf + off; off += (size_t)ROWS * HID;       // 4,096,000
    float* lsa    = wsf + off; off += (size_t)ROWS * HEADS;     // 256,000
    float* ldaf   = wsf + off; off += (size_t)ROWS * HEADS;
    float* lsbf   = wsf + off; off += (size_t)ROWS * HEADS;
    float* ldbf   = wsf + off; off += (size_t)ROWS * HEADS;
    float* wab    = wsf + off; off += NL * HCOL;                // 1,280
    float* wdb    = wsf + off; off += NL * HCOL;
    float* gib    = wsf + off; off += GOSZ;                     // 12,288
    float* hTb    = wsf + off; off += 256;
    u16* wphb     = (u16*)(wsf + off); off += NL * WPSZ / 2;    // 40,960 floats
    u16* wplb     = (u16*)(wsf + off); off += NL * WPSZ / 2;
    float* gip    = wsf + off; off += (size_t)KSPLIT * GOSZ;    // 6,144,000
    float* gip2   = wsf + off; off += 10 * GOSZ;                // 122,880
    int* ib = (int*)(wsf + off);
    int* src_e    = ib;          ib += EP;
    int* dst_e    = ib;          ib += EP;
    int* rowptr_p = ib;          ib += NNODE + 1;
    int* csr_src  = ib;          ib += EPAD;
    int* deg      = ib;          ib += NNODE;
    int* fill     = ib;          ib += NNODE;

    k_build_edges<<<(EP + 255) / 256, 256, 0, stream>>>(eidx, src_e, dst_e, deg, fill);
    k_csr_count<<<(EP + 255) / 256, 256, 0, stream>>>(dst_e, deg);
    k_csr_scan<<<1, 256, 0, stream>>>(deg, rowptr_p);
    k_csr_fill<<<(EP + 255) / 256, 256, 0, stream>>>(src_e, dst_e, rowptr_p, deg, fill, csr_src);

    k_wa<<<10, 256, 0, stream>>>(Wg, a_src, a_dst, wab, wdb);
    k_wpack<<<(NL * WPSZ + 255) / 256, 256, 0, stream>>>(Wg, wphb, wplb);

    k_input_fc<<<ROWS * 16 / 256, 256, 0, stream>>>(
        x_seq, (const float4*)W_in, (const float4*)b_in,
        (const float4*)wab, (const float4*)wdb, (float4*)x0a, (float4*)lsa, (float4*)ldaf);

    float* xc = x0a;  float* xn = x0b;
    float* lsc = lsa; float* ldc = ldaf;
    float* lsn = lsbf; float* ldn = ldbf;
    for (int l = 0; l < NL; l++) {
        const float4* wa_next = (l + 1 < NL) ? (const float4*)(wab + (size_t)(l + 1) * HCOL) : nullptr;
        const float4* wd_next = (l + 1 < NL) ? (const float4*)(wdb + (size_t)(l + 1) * HCOL) : nullptr;
        k_gat_fused<<<2048, 256, 0, stream>>>(
            (const float4*)xc, (const float4*)lsc, (const float4*)ldc,
            rowptr_p, csr_src, deg,
            wphb + (size_t)l * WPSZ, wplb + (size_t)l * WPSZ, bg + (size_t)l * HID,
            xn, wa_next, wd_next, (float4*)lsn, (float4*)ldn);
        float* t;
        t = xc; xc = xn; xn = t;
        t = lsc; lsc = lsn; lsn = t;
        t = ldc; ldc = ldn; ldn = t;
    }

    k_gi_gemm<<<KSPLIT, 256, 0, stream>>>(xc, W_ih, gip);
    k_gi_reduce1<<<dim3(GOSZ / 256, 10), 256, 0, stream>>>(gip, gip2);
    k_gi_reduce2<<<GOSZ / 256, 256, 0, stream>>>(gip2, b_ih, gib);
    k_gru<<<4, 192, 0, stream>>>(gib, W_hh, b_hh, hTb);
    k_final<<<(NB * NNODE + 255) / 256, 256, 0, stream>>>(hTb, W_fc, b_fc, out);
}

// Round 22
// 414.154 us; speedup vs baseline: 1.0092x; 1.0012x over previous
//
#include <hip/hip_runtime.h>
#include <math.h>

#define NB 4
#define TT 16
#define NNODE 1000
#define FIN 8
#define EE 8000
#define EP 9000          // E + N self loops
#define EPAD 16384       // max padded edges (pad rows to mult of 8)
#define HID 64
#define HEADS 4
#define NL 5
#define GG (NB*TT)       // 64 graphs
#define ROWS (GG*NNODE)  // 64000
#define HCOL (HEADS*HID) // 256
#define KGI (NNODE*HID)  // 64000
#define GOUT 192         // 3*HID
#define GIK 128          // K-slice per gi-gemm block
#define KSPLIT (KGI/GIK) // 500 partial slabs
#define GOSZ (GG*GOUT)   // 12288
#define WPSZ (8*4*64*8)  // 16384 packed W elems per layer

typedef unsigned short u16;
typedef __attribute__((ext_vector_type(8))) short short8;
typedef __attribute__((ext_vector_type(4))) float f32x4;

__device__ inline u16 f2bf(float f) {
    unsigned int u = __float_as_uint(f);
    unsigned int r = u + 0x7FFFu + ((u >> 16) & 1u);   // RNE
    return (u16)(r >> 16);
}
__device__ inline float bf2f(u16 h) {
    return __uint_as_float(((unsigned int)h) << 16);
}
__device__ inline ushort4 bfhi4(float4 a) {
    ushort4 r; r.x = f2bf(a.x); r.y = f2bf(a.y); r.z = f2bf(a.z); r.w = f2bf(a.w); return r;
}
__device__ inline ushort4 bflo4(float4 a, ushort4 h) {
    ushort4 r;
    r.x = f2bf(a.x - bf2f(h.x)); r.y = f2bf(a.y - bf2f(h.y));
    r.z = f2bf(a.z - bf2f(h.z)); r.w = f2bf(a.w - bf2f(h.w));
    return r;
}

// ---------------- edge prep ----------------
__global__ void k_build_edges(const int* __restrict__ eidx, int* __restrict__ src_e,
                              int* __restrict__ dst_e, int* __restrict__ deg, int* __restrict__ fill) {
    int i = blockIdx.x * blockDim.x + threadIdx.x;
    if (i < EP) {
        int s, d;
        if (i < EE) { s = eidx[i]; d = eidx[EE + i]; }
        else { s = i - EE; d = i - EE; }
        src_e[i] = s; dst_e[i] = d;
    }
    if (i < NNODE) { deg[i] = 0; fill[i] = 0; }
}

__global__ void k_csr_count(const int* __restrict__ dst_e, int* __restrict__ deg) {
    int i = blockIdx.x * blockDim.x + threadIdx.x;
    if (i < EP) atomicAdd(&deg[dst_e[i]], 1);
}

// parallel inclusive scan of PADDED degrees (pad to multiple of 8)
__global__ __launch_bounds__(256) void k_csr_scan(const int* __restrict__ deg, int* __restrict__ rowptr_p) {
    __shared__ int s[1024];
    int tid = threadIdx.x;
    for (int i = tid; i < 1024; i += 256) s[i] = (i < NNODE) ? ((deg[i] + 7) & ~7) : 0;
    __syncthreads();
    for (int off = 1; off < 1024; off <<= 1) {
        int t[4];
        #pragma unroll
        for (int q = 0; q < 4; q++) { int i = tid + 256 * q; t[q] = (i >= off) ? s[i - off] : 0; }
        __syncthreads();
        #pragma unroll
        for (int q = 0; q < 4; q++) { int i = tid + 256 * q; s[i] += t[q]; }
        __syncthreads();
    }
    for (int i = tid; i < NNODE; i += 256) rowptr_p[i + 1] = s[i];
    if (tid == 0) rowptr_p[0] = 0;
}

// fill CSR + pad slots (disjoint writes; pad needs only rowptr_p/deg, no ordering vs fill)
__global__ void k_csr_fill(const int* __restrict__ src_e, const int* __restrict__ dst_e,
                           const int* __restrict__ rowptr_p, const int* __restrict__ deg,
                           int* __restrict__ fill, int* __restrict__ csr_src) {
    int i = blockIdx.x * blockDim.x + threadIdx.x;
    if (i < EP) {
        int d = dst_e[i];
        int pos = atomicAdd(&fill[d], 1);
        csr_src[rowptr_p[d] + pos] = src_e[i];
    }
    if (i < NNODE) {
        int rs = rowptr_p[i], re = rowptr_p[i + 1];
        for (int j = rs + deg[i]; j < re; j++) csr_src[j] = i;
    }
}

// ---------------- precompute wa/wd: wa[l][j][h] = sum_c W_l[j, h*64+c] * a_src[l,h,c] ----------------
__global__ void k_wa(const float* __restrict__ Wg, const float* __restrict__ a_src,
                     const float* __restrict__ a_dst, float* __restrict__ wa, float* __restrict__ wd) {
    int t = blockIdx.x * 256 + threadIdx.x;      // 2*NL*HID*HEADS = 2560
    if (t >= 2 * NL * HID * HEADS) return;
    int kind = t >= NL * HID * HEADS;
    int u = t - kind * NL * HID * HEADS;
    int l = u >> 8;
    int rem = u & 255;
    int j = rem >> 2, hd = rem & 3;
    const float* a = (kind ? a_dst : a_src) + (size_t)l * HCOL + hd * HID;
    const float* Wl = Wg + (size_t)l * HID * HCOL + (size_t)j * HCOL + hd * HID;
    float acc = 0.f;
    #pragma unroll 8
    for (int c = 0; c < HID; c++) acc += Wl[c] * a[c];
    float* out = kind ? wd : wa;
    out[(size_t)l * HCOL + j * 4 + hd] = acc;
}

// ---------------- pack W into MFMA B-frag order, split bf16 hi/lo ----------------
// B frag layout (16x16x32): lane needs B[k=(lane>>4)*8+j][col=lane&15]
// wp[((l*8+ks)*4+ct)*512 + lane*8 + j] = W'[ks*32+(lane>>4)*8+j][ct*16+(lane&15)]
// where W'[k][c'] = Wg[l][k&63][(k>>6)*64+c']
__global__ void k_wpack(const float* __restrict__ Wg, u16* __restrict__ wph, u16* __restrict__ wpl) {
    int t = blockIdx.x * 256 + threadIdx.x;      // NL*WPSZ = 81920
    if (t >= NL * WPSZ) return;
    int j    = t & 7;
    int lane = (t >> 3) & 63;
    int ct   = (t >> 9) & 3;
    int ks   = (t >> 11) & 7;
    int l    = t >> 14;
    int k = ks * 32 + (lane >> 4) * 8 + j;
    int c = ct * 16 + (lane & 15);
    float v = Wg[(size_t)l * HID * HCOL + (size_t)(k & 63) * HCOL + (k >> 6) * 64 + c];
    u16 h = f2bf(v);
    wph[t] = h;
    wpl[t] = f2bf(v - bf2f(h));
}

// ---------------- input projection + fused layer-0 ls/ld ----------------
__global__ void k_input_fc(const float* __restrict__ xseq, const float4* __restrict__ Win4,
                           const float4* __restrict__ b_in4, const float4* __restrict__ wa04,
                           const float4* __restrict__ wd04, float4* __restrict__ x0,
                           float4* __restrict__ ls4, float4* __restrict__ ld4) {
    int idx = blockIdx.x * 256 + threadIdx.x;   // ROWS*16 threads
    int r = idx >> 4, c4 = idx & 15;
    float4 acc = b_in4[c4];
    #pragma unroll
    for (int k = 0; k < FIN; k++) {
        float xv = xseq[r * FIN + k];
        float4 w = Win4[k * 16 + c4];
        acc.x += xv * w.x; acc.y += xv * w.y; acc.z += xv * w.z; acc.w += xv * w.w;
    }
    x0[idx] = acc;
    float xr[4] = {acc.x, acc.y, acc.z, acc.w};
    float4 pls = make_float4(0.f, 0.f, 0.f, 0.f);
    float4 pld = make_float4(0.f, 0.f, 0.f, 0.f);
    #pragma unroll
    for (int jj = 0; jj < 4; jj++) {
        float4 wa_j = wa04[c4 * 4 + jj];
        float4 wd_j = wd04[c4 * 4 + jj];
        pls.x += xr[jj] * wa_j.x; pls.y += xr[jj] * wa_j.y;
        pls.z += xr[jj] * wa_j.z; pls.w += xr[jj] * wa_j.w;
        pld.x += xr[jj] * wd_j.x; pld.y += xr[jj] * wd_j.y;
        pld.z += xr[jj] * wd_j.z; pld.w += xr[jj] * wd_j.w;
    }
    #pragma unroll
    for (int o = 1; o < 16; o <<= 1) {
        pls.x += __shfl_xor(pls.x, o, 64); pls.y += __shfl_xor(pls.y, o, 64);
        pls.z += __shfl_xor(pls.z, o, 64); pls.w += __shfl_xor(pls.w, o, 64);
        pld.x += __shfl_xor(pld.x, o, 64); pld.y += __shfl_xor(pld.y, o, 64);
        pld.z += __shfl_xor(pld.z, o, 64); pld.w += __shfl_xor(pld.w, o, 64);
    }
    if (c4 == 0) {
        ls4[r] = pls;
        ld4[r] = pld;
    }
}

// ---------------- FUSED GAT layer: softmax+aggregate (y in LDS) -> MFMA GEMM -> ELU + next ls/ld ----
// Block = 256 thr, 32 nodes of one graph. Grid = 64 graphs x 32 blocks = 2048 (nodes 1000..1023 invalid).
// Agg: 4 waves x 4 nodes x 2 iters -> y tile (bf16 hi/lo) in LDS [32][264].
// BARRIERS inside it2 loop: the loop creates a cross-iteration WAR hazard on s_e/s_src (iteration 1's
// writes vs iteration 0's cross-lane gather reads) that the single-shot unfused kernel never had.
// GEMM: wave = 16 rows x 32 cols (2 ct tiles), A from LDS, B = packed W (L2). 3-term split-bf16.
// NOTE: reads layer-l state (x4/ls4/ld4), writes layer-(l+1) state -> MUST ping-pong buffers.
__global__ __launch_bounds__(256) void k_gat_fused(
        const float4* __restrict__ x4, const float4* __restrict__ ls4, const float4* __restrict__ ld4,
        const int* __restrict__ rowptr_p, const int* __restrict__ csr_src, const int* __restrict__ deg,
        const u16* __restrict__ wph, const u16* __restrict__ wpl, const float* __restrict__ bg,
        float* __restrict__ xout, const float4* __restrict__ wa4, const float4* __restrict__ wd4,
        float4* __restrict__ lso4, float4* __restrict__ ldo4) {
    __shared__ u16 yhs[32][264];          // 16.5 KB
    __shared__ u16 yls[32][264];          // 16.5 KB
    __shared__ float s_e[4][4][264];      // 16.9 KB (aliased as ls/ld partials in epilogue)
    __shared__ unsigned short s_src[4][4][64];  // 2 KB
    __shared__ float s_den[4][4][4];
    int b = blockIdx.x;
    int xcd = b & 7, sb = b >> 3;         // XCD round-robin: graph's 32 blocks on one XCD
    int g = xcd + 8 * (sb >> 5);          // graph 0..63
    int nb = (sb & 31) * 32;              // node base within graph
    int tid = threadIdx.x;
    int wid = tid >> 6, lane = tid & 63;
    int nsub = lane >> 4;                 // node slot 0..3
    int j0 = lane & 15;
    int c4 = lane & 15;
    const float4* lsg = ls4 + (size_t)g * NNODE;
    const float4* xg = x4 + (size_t)g * NNODE * 16 + c4;

    // ---------- aggregation phase: 2 iterations of 4 nodes per wave ----------
    for (int it2 = 0; it2 < 2; it2++) {
        __syncthreads();                  // protect prior iteration's s_e/s_src reads from this iter's writes
        int n_l = wid * 8 + it2 * 4 + nsub;   // local row 0..31
        int n_s = nb + n_l;                   // node in graph
        int valid = n_s < NNODE;
        int n_c = valid ? n_s : (NNODE - 1);  // clamped address
        int rs = rowptr_p[n_c];
        int dgp = valid ? (rowptr_p[n_c + 1] - rs) : 0;
        int dg = valid ? deg[n_c] : 0;
        int dg16 = (dgp + 15) & ~15;
        if (dg16 > 64) dg16 = 64;
        if (dgp > 64) dgp = 64;
        if (dg > 64) dg = 64;
        float4 ldv = ld4[(size_t)g * NNODE + n_c];

        // pass A: logits + running max (4-head float4 at s_e[..][j*4])
        float4 mx = make_float4(-1e30f, -1e30f, -1e30f, -1e30f);
        for (int base = 0; base < dg16; base += 16) {
            int j = base + j0;
            int sv = n_c;
            if (j < dgp) sv = csr_src[rs + j];
            s_src[wid][nsub][j] = (unsigned short)sv;
            float4 lo = make_float4(-1e30f, -1e30f, -1e30f, -1e30f);
            if (j < dg) {
                float4 t = lsg[sv];
                t.x += ldv.x; t.y += ldv.y; t.z += ldv.z; t.w += ldv.w;
                t.x = fmaxf(t.x, 0.2f * t.x); t.y = fmaxf(t.y, 0.2f * t.y);
                t.z = fmaxf(t.z, 0.2f * t.z); t.w = fmaxf(t.w, 0.2f * t.w);
                lo = t;
                mx.x = fmaxf(mx.x, lo.x); mx.y = fmaxf(mx.y, lo.y);
                mx.z = fmaxf(mx.z, lo.z); mx.w = fmaxf(mx.w, lo.w);
            }
            *reinterpret_cast<float4*>(&s_e[wid][nsub][j * 4]) = lo;
        }
        #pragma unroll
        for (int o = 1; o < 16; o <<= 1) {
            mx.x = fmaxf(mx.x, __shfl_xor(mx.x, o, 64));
            mx.y = fmaxf(mx.y, __shfl_xor(mx.y, o, 64));
            mx.z = fmaxf(mx.z, __shfl_xor(mx.z, o, 64));
            mx.w = fmaxf(mx.w, __shfl_xor(mx.w, o, 64));
        }
        // pass B: exp + denominator
        float4 den = make_float4(0.f, 0.f, 0.f, 0.f);
        for (int base = 0; base < dg16; base += 16) {
            int j = base + j0;
            float4 e = make_float4(0.f, 0.f, 0.f, 0.f);
            if (j < dg) {
                float4 lo = *reinterpret_cast<const float4*>(&s_e[wid][nsub][j * 4]);
                e.x = __expf(lo.x - mx.x);
                e.y = __expf(lo.y - mx.y);
                e.z = __expf(lo.z - mx.z);
                e.w = __expf(lo.w - mx.w);
            }
            den.x += e.x; den.y += e.y; den.z += e.z; den.w += e.w;
            *reinterpret_cast<float4*>(&s_e[wid][nsub][j * 4]) = e;
        }
        #pragma unroll
        for (int o = 1; o < 16; o <<= 1) {
            den.x += __shfl_xor(den.x, o, 64);
            den.y += __shfl_xor(den.y, o, 64);
            den.z += __shfl_xor(den.z, o, 64);
            den.w += __shfl_xor(den.w, o, 64);
        }
        if (j0 == 0) *reinterpret_cast<float4*>(&s_den[wid][nsub][0]) = den;
        __syncthreads();                  // all s_e/s_den/s_src writes visible before gather

        // gather: lane (nsub,c4) owns one node's col slice, all 4 heads
        float4 a0 = make_float4(0.f, 0.f, 0.f, 0.f);
        float4 a1 = a0, a2 = a0, a3 = a0;
        const float* ep = &s_e[wid][nsub][0];
        const unsigned short* sp = &s_src[wid][nsub][0];
        int dg4 = (dg + 3) & ~3;
        int q = 0;
        for (; q + 8 <= dg4; q += 8) {
            int sj[8]; float4 ev[8], xv[8];
            #pragma unroll
            for (int u = 0; u < 8; u++) sj[u] = sp[q + u];
            #pragma unroll
            for (int u = 0; u < 8; u++) xv[u] = xg[(size_t)sj[u] * 16];
            #pragma unroll
            for (int u = 0; u < 8; u++) ev[u] = *reinterpret_cast<const float4*>(&ep[(q + u) * 4]);
            #pragma unroll
            for (int u = 0; u < 8; u++) {
                a0.x += ev[u].x * xv[u].x; a0.y += ev[u].x * xv[u].y;
                a0.z += ev[u].x * xv[u].z; a0.w += ev[u].x * xv[u].w;
                a1.x += ev[u].y * xv[u].x; a1.y += ev[u].y * xv[u].y;
                a1.z += ev[u].y * xv[u].z; a1.w += ev[u].y * xv[u].w;
                a2.x += ev[u].z * xv[u].x; a2.y += ev[u].z * xv[u].y;
                a2.z += ev[u].z * xv[u].z; a2.w += ev[u].z * xv[u].w;
                a3.x += ev[u].w * xv[u].x; a3.y += ev[u].w * xv[u].y;
                a3.z += ev[u].w * xv[u].z; a3.w += ev[u].w * xv[u].w;
            }
        }
        if (q < dg4) {
            int sj[4]; float4 ev[4], xv[4];
            #pragma unroll
            for (int u = 0; u < 4; u++) sj[u] = sp[q + u];
            #pragma unroll
            for (int u = 0; u < 4; u++) xv[u] = xg[(size_t)sj[u] * 16];
            #pragma unroll
            for (int u = 0; u < 4; u++) ev[u] = *reinterpret_cast<const float4*>(&ep[(q + u) * 4]);
            #pragma unroll
            for (int u = 0; u < 4; u++) {
                a0.x += ev[u].x * xv[u].x; a0.y += ev[u].x * xv[u].y;
                a0.z += ev[u].x * xv[u].z; a0.w += ev[u].x * xv[u].w;
                a1.x += ev[u].y * xv[u].x; a1.y += ev[u].y * xv[u].y;
                a1.z += ev[u].y * xv[u].z; a1.w += ev[u].y * xv[u].w;
                a2.x += ev[u].z * xv[u].x; a2.y += ev[u].z * xv[u].y;
                a2.z += ev[u].z * xv[u].z; a2.w += ev[u].z * xv[u].w;
                a3.x += ev[u].w * xv[u].x; a3.y += ev[u].w * xv[u].y;
                a3.z += ev[u].w * xv[u].z; a3.w += ev[u].w * xv[u].w;
            }
        }
        float4 dv = *reinterpret_cast<const float4*>(&s_den[wid][nsub][0]);
        float i0 = 1.f / (dv.x + 1e-16f), i1 = 1.f / (dv.y + 1e-16f);
        float i2 = 1.f / (dv.z + 1e-16f), i3 = 1.f / (dv.w + 1e-16f);
        a0.x *= i0; a0.y *= i0; a0.z *= i0; a0.w *= i0;
        a1.x *= i1; a1.y *= i1; a1.z *= i1; a1.w *= i1;
        a2.x *= i2; a2.y *= i2; a2.z *= i2; a2.w *= i2;
        a3.x *= i3; a3.y *= i3; a3.z *= i3; a3.w *= i3;
        ushort4 h0 = bfhi4(a0), h1 = bfhi4(a1), h2 = bfhi4(a2), h3 = bfhi4(a3);
        *reinterpret_cast<ushort4*>(&yhs[n_l][0 * 64 + c4 * 4]) = h0;
        *reinterpret_cast<ushort4*>(&yhs[n_l][1 * 64 + c4 * 4]) = h1;
        *reinterpret_cast<ushort4*>(&yhs[n_l][2 * 64 + c4 * 4]) = h2;
        *reinterpret_cast<ushort4*>(&yhs[n_l][3 * 64 + c4 * 4]) = h3;
        *reinterpret_cast<ushort4*>(&yls[n_l][0 * 64 + c4 * 4]) = bflo4(a0, h0);
        *reinterpret_cast<ushort4*>(&yls[n_l][1 * 64 + c4 * 4]) = bflo4(a1, h1);
        *reinterpret_cast<ushort4*>(&yls[n_l][2 * 64 + c4 * 4]) = bflo4(a2, h2);
        *reinterpret_cast<ushort4*>(&yls[n_l][3 * 64 + c4 * 4]) = bflo4(a3, h3);
    }
    __syncthreads();

    // ---------- GEMM phase: wave = rows (wid&1)*16..+16, cols (wid>>1)*32..+32 ----------
    int r0l = (wid & 1) * 16;
    int ch = wid >> 1;
    int arow = lane & 15, kg = lane >> 4;
    f32x4 acc0 = {0.f, 0.f, 0.f, 0.f};
    f32x4 acc1 = {0.f, 0.f, 0.f, 0.f};
    const short8* bh8 = reinterpret_cast<const short8*>(wph) + lane;
    const short8* bl8 = reinterpret_cast<const short8*>(wpl) + lane;
    #pragma unroll
    for (int ks = 0; ks < 8; ks++) {
        short8 ah = *reinterpret_cast<const short8*>(&yhs[r0l + arow][ks * 32 + kg * 8]);
        short8 al = *reinterpret_cast<const short8*>(&yls[r0l + arow][ks * 32 + kg * 8]);
        #pragma unroll
        for (int ctl = 0; ctl < 2; ctl++) {
            int ctg = ch * 2 + ctl;
            short8 bh = bh8[(size_t)(ks * 4 + ctg) * 64];
            short8 bl = bl8[(size_t)(ks * 4 + ctg) * 64];
            f32x4* ac = ctl ? &acc1 : &acc0;
            *ac = __builtin_amdgcn_mfma_f32_16x16x32_bf16(ah, bh, *ac, 0, 0, 0);
            *ac = __builtin_amdgcn_mfma_f32_16x16x32_bf16(ah, bl, *ac, 0, 0, 0);
            *ac = __builtin_amdgcn_mfma_f32_16x16x32_bf16(al, bh, *ac, 0, 0, 0);
        }
    }

    // epilogue: bias + ELU + store xout; D layout col=lane&15, row=(lane>>4)*4+reg
    float ev2[2][4];
    #pragma unroll
    for (int ctl = 0; ctl < 2; ctl++) {
        int c = (ch * 2 + ctl) * 16 + arow;
        float bc = bg[c];
        f32x4 a = ctl ? acc1 : acc0;
        #pragma unroll
        for (int r = 0; r < 4; r++) {
            int node = nb + r0l + kg * 4 + r;
            float v = a[r] * 0.25f + bc;
            float e = v > 0.f ? v : expm1f(v);
            ev2[ctl][r] = e;
            if (node < NNODE)
                xout[((size_t)g * NNODE + node) * HID + c] = e;
        }
    }
    if (wa4) {
        float* s_part = &s_e[0][0][0];    // [2][32][8] floats, s_e dead after barrier above
        __syncthreads();                  // ensure all waves done with s_e (gather) before aliasing
        #pragma unroll
        for (int r = 0; r < 4; r++) {
            float4 pls = make_float4(0.f, 0.f, 0.f, 0.f);
            float4 pld = make_float4(0.f, 0.f, 0.f, 0.f);
            #pragma unroll
            for (int ctl = 0; ctl < 2; ctl++) {
                int c = (ch * 2 + ctl) * 16 + arow;
                float e = ev2[ctl][r];
                float4 wa_c = wa4[c];
                float4 wd_c = wd4[c];
                pls.x += e * wa_c.x; pls.y += e * wa_c.y;
                pls.z += e * wa_c.z; pls.w += e * wa_c.w;
                pld.x += e * wd_c.x; pld.y += e * wd_c.y;
                pld.z += e * wd_c.z; pld.w += e * wd_c.w;
            }
            #pragma unroll
            for (int o = 1; o < 16; o <<= 1) {
                pls.x += __shfl_xor(pls.x, o, 64); pls.y += __shfl_xor(pls.y, o, 64);
                pls.z += __shfl_xor(pls.z, o, 64); pls.w += __shfl_xor(pls.w, o, 64);
                pld.x += __shfl_xor(pld.x, o, 64); pld.y += __shfl_xor(pld.y, o, 64);
                pld.z += __shfl_xor(pld.z, o, 64); pld.w += __shfl_xor(pld.w, o, 64);
            }
            if (arow == 0) {
                int rl = r0l + kg * 4 + r;
                float4* p = reinterpret_cast<float4*>(&s_part[(ch * 32 + rl) * 8]);
                p[0] = pls; p[1] = pld;
            }
        }
        __syncthreads();
        int rl = tid >> 3, cc = tid & 7;  // 32 rows x 8 components
        int node = nb + rl;
        if (node < NNODE) {
            float v = s_part[rl * 8 + cc] + s_part[(32 + rl) * 8 + cc];
            float* dst = (cc < 4) ? reinterpret_cast<float*>(lso4) : reinterpret_cast<float*>(ldo4);
            dst[((size_t)g * NNODE + node) * 4 + (cc & 3)] = v;
        }
    }
}

// ---------------- GRU input GEMM: 500 K-slices, full 64x192 tile/block, no atomics ----------------
__global__ __launch_bounds__(256) void k_gi_gemm(const float* __restrict__ x, const float* __restrict__ W_ih,
                                                 float* __restrict__ gip) {
    __shared__ float xs[32 * 68];    // [kk][row], pitch 68
    __shared__ float ws[32 * 196];   // [kk][col 0..191], pitch 196
    int k0 = blockIdx.x * GIK;
    int tid = threadIdx.x;
    int lane = tid & 63;
    int wv = tid >> 6;
    int tx = tid & 15, ty = tid >> 4;
    float4 accs[4][3];
    #pragma unroll
    for (int i = 0; i < 4; i++)
        #pragma unroll
        for (int j = 0; j < 3; j++) accs[i][j] = make_float4(0.f, 0.f, 0.f, 0.f);

    for (int kt = 0; kt < GIK / 32; kt++) {
        int kb = k0 + kt * 32;
        #pragma unroll
        for (int it = 0; it < 2; it++) {
            int kq = wv + 4 * it;
            float4 v = *reinterpret_cast<const float4*>(&x[(size_t)lane * KGI + kb + kq * 4]);
            int k = kq * 4;
            xs[(k + 0) * 68 + lane] = v.x;
            xs[(k + 1) * 68 + lane] = v.y;
            xs[(k + 2) * 68 + lane] = v.z;
            xs[(k + 3) * 68 + lane] = v.w;
        }
        #pragma unroll
        for (int cg = 0; cg < 3; cg++) {
            #pragma unroll
            for (int it = 0; it < 2; it++) {
                int kq = wv + 4 * it;
                int c = cg * 64 + lane;
                float4 v = *reinterpret_cast<const float4*>(&W_ih[(size_t)c * KGI + kb + kq * 4]);
                int k = kq * 4;
                ws[(k + 0) * 196 + c] = v.x;
                ws[(k + 1) * 196 + c] = v.y;
                ws[(k + 2) * 196 + c] = v.z;
                ws[(k + 3) * 196 + c] = v.w;
            }
        }
        __syncthreads();
        for (int kk = 0; kk < 32; kk++) {
            float4 xv = *reinterpret_cast<const float4*>(&xs[kk * 68 + ty * 4]);
            float4 w0 = *reinterpret_cast<const float4*>(&ws[kk * 196 + tx * 4]);
            float4 w1 = *reinterpret_cast<const float4*>(&ws[kk * 196 + 64 + tx * 4]);
            float4 w2 = *reinterpret_cast<const float4*>(&ws[kk * 196 + 128 + tx * 4]);
            #pragma unroll
            for (int i = 0; i < 4; i++) {
                float xi = (i == 0) ? xv.x : (i == 1) ? xv.y : (i == 2) ? xv.z : xv.w;
                accs[i][0].x += xi * w0.x; accs[i][0].y += xi * w0.y; accs[i][0].z += xi * w0.z; accs[i][0].w += xi * w0.w;
                accs[i][1].x += xi * w1.x; accs[i][1].y += xi * w1.y; accs[i][1].z += xi * w1.z; accs[i][1].w += xi * w1.w;
                accs[i][2].x += xi * w2.x; accs[i][2].y += xi * w2.y; accs[i][2].z += xi * w2.z; accs[i][2].w += xi * w2.w;
            }
        }
        __syncthreads();
    }
    float* out = gip + (size_t)blockIdx.x * GOSZ;
    #pragma unroll
    for (int i = 0; i < 4; i++)
        #pragma unroll
        for (int j = 0; j < 3; j++)
            *reinterpret_cast<float4*>(&out[(ty * 4 + i) * GOUT + j * 64 + tx * 4]) = accs[i][j];
}

__global__ void k_gi_reduce1(const float* __restrict__ gip, float* __restrict__ gip2) {
    int idx = blockIdx.x * 256 + threadIdx.x;     // 0..GOSZ-1
    const float* p = gip + (size_t)blockIdx.y * 50 * GOSZ + idx;
    float a = 0.f;
    #pragma unroll 5
    for (int s = 0; s < 50; s++) a += p[(size_t)s * GOSZ];
    gip2[blockIdx.y * GOSZ + idx] = a;
}

__global__ void k_gi_reduce2(const float* __restrict__ gip2, const float* __restrict__ b_ih,
                             float* __restrict__ gi) {
    int idx = blockIdx.x * 256 + threadIdx.x;
    float a = b_ih[idx % GOUT];
    #pragma unroll
    for (int y = 0; y < 10; y++) a += gip2[(size_t)y * GOSZ + idx];
    gi[idx] = a;
}

// ---------------- GRU scan: one block per batch, W_hh row in registers, LDS broadcast hs ----------------
__global__ __launch_bounds__(192) void k_gru(const float* __restrict__ gi, const float* __restrict__ W_hh,
                                             const float* __restrict__ b_hh, float* __restrict__ hT) {
    __shared__ float hs[64];
    __shared__ float gh[192];
    int j = threadIdx.x;      // 0..191
    int b = blockIdx.x;       // 0..3
    float wrow[64];
    #pragma unroll
    for (int q = 0; q < 16; q++) {
        float4 v = *reinterpret_cast<const float4*>(&W_hh[(size_t)j * 64 + q * 4]);
        wrow[q * 4 + 0] = v.x; wrow[q * 4 + 1] = v.y;
        wrow[q * 4 + 2] = v.z; wrow[q * 4 + 3] = v.w;
    }
    float bj = b_hh[j];
    if (j < 64) hs[j] = 0.f;
    __syncthreads();
    for (int t = 0; t < TT; t++) {
        float a0 = 0.f, a1 = 0.f, a2 = 0.f, a3 = 0.f;
        #pragma unroll
        for (int q = 0; q < 16; q++) {
            float4 h4 = *reinterpret_cast<const float4*>(&hs[q * 4]);   // broadcast read
            a0 += h4.x * wrow[q * 4 + 0];
            a1 += h4.y * wrow[q * 4 + 1];
            a2 += h4.z * wrow[q * 4 + 2];
            a3 += h4.w * wrow[q * 4 + 3];
        }
        gh[j] = bj + ((a0 + a1) + (a2 + a3));
        __syncthreads();
        if (j < 64) {
            int row = (b * TT + t) * GOUT;
            float ir = gi[row + j], iz = gi[row + 64 + j], in_ = gi[row + 128 + j];
            float r = 1.f / (1.f + expf(-(ir + gh[j])));
            float z = 1.f / (1.f + expf(-(iz + gh[64 + j])));
            float nv = tanhf(in_ + r * gh[128 + j]);
            hs[j] = (1.f - z) * nv + z * hs[j];
        }
        __syncthreads();
    }
    if (j < 64) hT[b * 64 + j] = hs[j];
}

// ---------------- final FC ----------------
__global__ void k_final(const float* __restrict__ hT, const float* __restrict__ W_fc,
                        const float* __restrict__ b_fc, float* __restrict__ out) {
    int idx = blockIdx.x * 256 + threadIdx.x;
    if (idx >= NB * NNODE) return;
    int b = idx / NNODE, n = idx % NNODE;
    float acc = b_fc[n];
    #pragma unroll
    for (int c = 0; c < HID; c++) acc += hT[b * HID + c] * W_fc[c * NNODE + n];
    out[idx] = acc;
}

extern "C" void kernel_launch(void* const* d_in, const int* in_sizes, int n_in,
                              void* d_out, int out_size, void* d_ws, size_t ws_size,
                              hipStream_t stream) {
    const float* x_seq  = (const float*)d_in[0];
    const int*   eidx   = (const int*)  d_in[1];
    // d_in[2] edge_weight: unused by GATConv
    const float* W_in   = (const float*)d_in[3];
    const float* b_in   = (const float*)d_in[4];
    const float* Wg     = (const float*)d_in[5];
    const float* a_src  = (const float*)d_in[6];
    const float* a_dst  = (const float*)d_in[7];
    const float* bg     = (const float*)d_in[8];
    const float* W_ih   = (const float*)d_in[9];
    const float* W_hh   = (const float*)d_in[10];
    const float* b_ih   = (const float*)d_in[11];
    const float* b_hh   = (const float*)d_in[12];
    const float* W_fc   = (const float*)d_in[13];
    const float* b_fc   = (const float*)d_in[14];
    float* out = (float*)d_out;

    float* wsf = (float*)d_ws;
    size_t off = 0;
    float* x0a    = wsf + off; off += (size_t)ROWS * HID;       // 4,096,000 floats
    float* x0b    = wsf + off; off += (size_t)ROWS * HID;       // 4,096,000
    float* lsa    = wsf + off; off += (size_t)ROWS * HEADS;     // 256,000
    float* ldaf   = wsf + off; off += (size_t)ROWS * HEADS;
    float* lsbf   = wsf + off; off += (size_t)ROWS * HEADS;
    float* ldbf   = wsf + off; off += (size_t)ROWS * HEADS;
    float* wab    = wsf + off; off += NL * HCOL;                // 1,280
    float* wdb    = wsf + off; off += NL * HCOL;
    float* gib    = wsf + off; off += GOSZ;                     // 12,288
    float* hTb    = wsf + off; off += 256;
    u16* wphb     = (u16*)(wsf + off); off += NL * WPSZ / 2;    // 40,960 floats
    u16* wplb     = (u16*)(wsf + off); off += NL * WPSZ / 2;
    float* gip    = wsf + off; off += (size_t)KSPLIT * GOSZ;    // 6,144,000
    float* gip2   = wsf + off; off += 10 * GOSZ;                // 122,880
    int* ib = (int*)(wsf + off);
    int* src_e    = ib;          ib += EP;
    int* dst_e    = ib;          ib += EP;
    int* rowptr_p = ib;          ib += NNODE + 1;
    int* csr_src  = ib;          ib += EPAD;
    int* deg      = ib;          ib += NNODE;
    int* fill     = ib;          ib += NNODE;

    k_build_edges<<<(EP + 255) / 256, 256, 0, stream>>>(eidx, src_e, dst_e, deg, fill);
    k_csr_count<<<(EP + 255) / 256, 256, 0, stream>>>(dst_e, deg);
    k_csr_scan<<<1, 256, 0, stream>>>(deg, rowptr_p);
    k_csr_fill<<<(EP + 255) / 256, 256, 0, stream>>>(src_e, dst_e, rowptr_p, deg, fill, csr_src);

    k_wa<<<10, 256, 0, stream>>>(Wg, a_src, a_dst, wab, wdb);
    k_wpack<<<(NL * WPSZ + 255) / 256, 256, 0, stream>>>(Wg, wphb, wplb);

    k_input_fc<<<ROWS * 16 / 256, 256, 0, stream>>>(
        x_seq, (const float4*)W_in, (const float4*)b_in,
        (const float4*)wab, (const float4*)wdb, (float4*)x0a, (float4*)lsa, (float4*)ldaf);

    float* xc = x0a;  float* xn = x0b;
    float* lsc = lsa; float* ldc = ldaf;
    float* lsn = lsbf; float* ldn = ldbf;
    for (int l = 0; l < NL; l++) {
        const float4* wa_next = (l + 1 < NL) ? (const float4*)(wab + (size_t)(l + 1) * HCOL) : nullptr;
        const float4* wd_next = (l + 1 < NL) ? (const float4*)(wdb + (size_t)(l + 1) * HCOL) : nullptr;
        k_gat_fused<<<2048, 256, 0, stream>>>(
            (const float4*)xc, (const float4*)lsc, (const float4*)ldc,
            rowptr_p, csr_src, deg,
            wphb + (size_t)l * WPSZ, wplb + (size_t)l * WPSZ, bg + (size_t)l * HID,
            xn, wa_next, wd_next, (float4*)lsn, (float4*)ldn);
        float* t;
        t = xc; xc = xn; xn = t;
        t = lsc; lsc = lsn; lsn = t;
        t = ldc; ldc = ldn; ldn = t;
    }

    k_gi_gemm<<<KSPLIT, 256, 0, stream>>>(xc, W_ih, gip);
    k_gi_reduce1<<<dim3(GOSZ / 256, 10), 256, 0, stream>>>(gip, gip2);
    k_gi_reduce2<<<GOSZ / 256, 256, 0, stream>>>(gip2, b_ih, gib);
    k_gru<<<4, 192, 0, stream>>>(gib, W_hh, b_hh, hTb);
    k_final<<<(NB * NNODE + 255) / 256, 256, 0, stream>>>(hTb, W_fc, b_fc, out);
}

// Round 23
// 414.100 us; speedup vs baseline: 1.0093x; 1.0001x over previous
//
#include <hip/hip_runtime.h>
#include <math.h>

#define NB 4
#define TT 16
#define NNODE 1000
#define FIN 8
#define EE 8000
#define EP 9000          // E + N self loops
#define EPAD 16384       // max padded edges (pad rows to mult of 8)
#define HID 64
#define HEADS 4
#define NL 5
#define GG (NB*TT)       // 64 graphs
#define ROWS (GG*NNODE)  // 64000
#define HCOL (HEADS*HID) // 256
#define KGI (NNODE*HID)  // 64000
#define GOUT 192         // 3*HID
#define GIK 128          // K-slice per gi-gemm block
#define KSPLIT (KGI/GIK) // 500 partial slabs
#define GOSZ (GG*GOUT)   // 12288
#define WPSZ (8*4*64*8)  // 16384 packed W elems per layer

typedef unsigned short u16;
typedef __attribute__((ext_vector_type(8))) short short8;
typedef __attribute__((ext_vector_type(4))) float f32x4;

__device__ inline u16 f2bf(float f) {
    unsigned int u = __float_as_uint(f);
    unsigned int r = u + 0x7FFFu + ((u >> 16) & 1u);   // RNE
    return (u16)(r >> 16);
}
__device__ inline float bf2f(u16 h) {
    return __uint_as_float(((unsigned int)h) << 16);
}
__device__ inline ushort4 bfhi4(float4 a) {
    ushort4 r; r.x = f2bf(a.x); r.y = f2bf(a.y); r.z = f2bf(a.z); r.w = f2bf(a.w); return r;
}
__device__ inline ushort4 bflo4(float4 a, ushort4 h) {
    ushort4 r;
    r.x = f2bf(a.x - bf2f(h.x)); r.y = f2bf(a.y - bf2f(h.y));
    r.z = f2bf(a.z - bf2f(h.z)); r.w = f2bf(a.w - bf2f(h.w));
    return r;
}

// ---------------- edge prep ----------------
__global__ void k_build_edges(const int* __restrict__ eidx, int* __restrict__ src_e,
                              int* __restrict__ dst_e, int* __restrict__ deg, int* __restrict__ fill) {
    int i = blockIdx.x * blockDim.x + threadIdx.x;
    if (i < EP) {
        int s, d;
        if (i < EE) { s = eidx[i]; d = eidx[EE + i]; }
        else { s = i - EE; d = i - EE; }
        src_e[i] = s; dst_e[i] = d;
    }
    if (i < NNODE) { deg[i] = 0; fill[i] = 0; }
}

__global__ void k_csr_count(const int* __restrict__ dst_e, int* __restrict__ deg) {
    int i = blockIdx.x * blockDim.x + threadIdx.x;
    if (i < EP) atomicAdd(&deg[dst_e[i]], 1);
}

// parallel inclusive scan of PADDED degrees (pad to multiple of 8)
__global__ __launch_bounds__(256) void k_csr_scan(const int* __restrict__ deg, int* __restrict__ rowptr_p) {
    __shared__ int s[1024];
    int tid = threadIdx.x;
    for (int i = tid; i < 1024; i += 256) s[i] = (i < NNODE) ? ((deg[i] + 7) & ~7) : 0;
    __syncthreads();
    for (int off = 1; off < 1024; off <<= 1) {
        int t[4];
        #pragma unroll
        for (int q = 0; q < 4; q++) { int i = tid + 256 * q; t[q] = (i >= off) ? s[i - off] : 0; }
        __syncthreads();
        #pragma unroll
        for (int q = 0; q < 4; q++) { int i = tid + 256 * q; s[i] += t[q]; }
        __syncthreads();
    }
    for (int i = tid; i < NNODE; i += 256) rowptr_p[i + 1] = s[i];
    if (tid == 0) rowptr_p[0] = 0;
}

// fill CSR + pad slots (disjoint writes; pad needs only rowptr_p/deg, no ordering vs fill)
__global__ void k_csr_fill(const int* __restrict__ src_e, const int* __restrict__ dst_e,
                           const int* __restrict__ rowptr_p, const int* __restrict__ deg,
                           int* __restrict__ fill, int* __restrict__ csr_src) {
    int i = blockIdx.x * blockDim.x + threadIdx.x;
    if (i < EP) {
        int d = dst_e[i];
        int pos = atomicAdd(&fill[d], 1);
        csr_src[rowptr_p[d] + pos] = src_e[i];
    }
    if (i < NNODE) {
        int rs = rowptr_p[i], re = rowptr_p[i + 1];
        for (int j = rs + deg[i]; j < re; j++) csr_src[j] = i;
    }
}

// ---------------- precompute wa/wd: wa[l][j][h] = sum_c W_l[j, h*64+c] * a_src[l,h,c] ----------------
__global__ void k_wa(const float* __restrict__ Wg, const float* __restrict__ a_src,
                     const float* __restrict__ a_dst, float* __restrict__ wa, float* __restrict__ wd) {
    int t = blockIdx.x * 256 + threadIdx.x;      // 2*NL*HID*HEADS = 2560
    if (t >= 2 * NL * HID * HEADS) return;
    int kind = t >= NL * HID * HEADS;
    int u = t - kind * NL * HID * HEADS;
    int l = u >> 8;
    int rem = u & 255;
    int j = rem >> 2, hd = rem & 3;
    const float* a = (kind ? a_dst : a_src) + (size_t)l * HCOL + hd * HID;
    const float* Wl = Wg + (size_t)l * HID * HCOL + (size_t)j * HCOL + hd * HID;
    float acc = 0.f;
    #pragma unroll 8
    for (int c = 0; c < HID; c++) acc += Wl[c] * a[c];
    float* out = kind ? wd : wa;
    out[(size_t)l * HCOL + j * 4 + hd] = acc;
}

// ---------------- pack W into MFMA B-frag order, split bf16 hi/lo ----------------
// B frag layout (16x16x32): lane needs B[k=(lane>>4)*8+j][col=lane&15]
// wp[((l*8+ks)*4+ct)*512 + lane*8 + j] = W'[ks*32+(lane>>4)*8+j][ct*16+(lane&15)]
// where W'[k][c'] = Wg[l][k&63][(k>>6)*64+c']
__global__ void k_wpack(const float* __restrict__ Wg, u16* __restrict__ wph, u16* __restrict__ wpl) {
    int t = blockIdx.x * 256 + threadIdx.x;      // NL*WPSZ = 81920
    if (t >= NL * WPSZ) return;
    int j    = t & 7;
    int lane = (t >> 3) & 63;
    int ct   = (t >> 9) & 3;
    int ks   = (t >> 11) & 7;
    int l    = t >> 14;
    int k = ks * 32 + (lane >> 4) * 8 + j;
    int c = ct * 16 + (lane & 15);
    float v = Wg[(size_t)l * HID * HCOL + (size_t)(k & 63) * HCOL + (k >> 6) * 64 + c];
    u16 h = f2bf(v);
    wph[t] = h;
    wpl[t] = f2bf(v - bf2f(h));
}

// ---------------- input projection + fused layer-0 ls/ld ----------------
__global__ void k_input_fc(const float* __restrict__ xseq, const float4* __restrict__ Win4,
                           const float4* __restrict__ b_in4, const float4* __restrict__ wa04,
                           const float4* __restrict__ wd04, float4* __restrict__ x0,
                           float4* __restrict__ ls4, float4* __restrict__ ld4) {
    int idx = blockIdx.x * 256 + threadIdx.x;   // ROWS*16 threads
    int r = idx >> 4, c4 = idx & 15;
    float4 acc = b_in4[c4];
    #pragma unroll
    for (int k = 0; k < FIN; k++) {
        float xv = xseq[r * FIN + k];
        float4 w = Win4[k * 16 + c4];
        acc.x += xv * w.x; acc.y += xv * w.y; acc.z += xv * w.z; acc.w += xv * w.w;
    }
    x0[idx] = acc;
    float xr[4] = {acc.x, acc.y, acc.z, acc.w};
    float4 pls = make_float4(0.f, 0.f, 0.f, 0.f);
    float4 pld = make_float4(0.f, 0.f, 0.f, 0.f);
    #pragma unroll
    for (int jj = 0; jj < 4; jj++) {
        float4 wa_j = wa04[c4 * 4 + jj];
        float4 wd_j = wd04[c4 * 4 + jj];
        pls.x += xr[jj] * wa_j.x; pls.y += xr[jj] * wa_j.y;
        pls.z += xr[jj] * wa_j.z; pls.w += xr[jj] * wa_j.w;
        pld.x += xr[jj] * wd_j.x; pld.y += xr[jj] * wd_j.y;
        pld.z += xr[jj] * wd_j.z; pld.w += xr[jj] * wd_j.w;
    }
    #pragma unroll
    for (int o = 1; o < 16; o <<= 1) {
        pls.x += __shfl_xor(pls.x, o, 64); pls.y += __shfl_xor(pls.y, o, 64);
        pls.z += __shfl_xor(pls.z, o, 64); pls.w += __shfl_xor(pls.w, o, 64);
        pld.x += __shfl_xor(pld.x, o, 64); pld.y += __shfl_xor(pld.y, o, 64);
        pld.z += __shfl_xor(pld.z, o, 64); pld.w += __shfl_xor(pld.w, o, 64);
    }
    if (c4 == 0) {
        ls4[r] = pls;
        ld4[r] = pld;
    }
}

// ---------------- FUSED GAT layer: softmax+aggregate (y in LDS) -> MFMA GEMM -> ELU + next ls/ld ----
// Block = 256 thr, 32 nodes of one graph. Grid = 64 graphs x 32 blocks = 2048 (nodes 1000..1023 invalid).
// Agg: 4 waves x 4 nodes x 2 iters -> y tile (bf16 hi/lo) in LDS [32][264].
// BARRIERS inside it2 loop: the loop creates a cross-iteration WAR hazard on s_e/s_src (iteration 1's
// writes vs iteration 0's cross-lane gather reads) that the single-shot unfused kernel never had.
// GEMM: wave = 16 rows x 32 cols (2 ct tiles), A from LDS, B = packed W (L2). 3-term split-bf16.
// NOTE: reads layer-l state (x4/ls4/ld4), writes layer-(l+1) state -> MUST ping-pong buffers.
__global__ __launch_bounds__(256) void k_gat_fused(
        const float4* __restrict__ x4, const float4* __restrict__ ls4, const float4* __restrict__ ld4,
        const int* __restrict__ rowptr_p, const int* __restrict__ csr_src, const int* __restrict__ deg,
        const u16* __restrict__ wph, const u16* __restrict__ wpl, const float* __restrict__ bg,
        float* __restrict__ xout, const float4* __restrict__ wa4, const float4* __restrict__ wd4,
        float4* __restrict__ lso4, float4* __restrict__ ldo4) {
    __shared__ u16 yhs[32][264];          // 16.5 KB
    __shared__ u16 yls[32][264];          // 16.5 KB
    __shared__ float s_e[4][4][264];      // 16.9 KB (aliased as ls/ld partials in epilogue)
    __shared__ unsigned short s_src[4][4][64];  // 2 KB
    __shared__ float s_den[4][4][4];
    int b = blockIdx.x;
    int xcd = b & 7, sb = b >> 3;         // XCD round-robin: graph's 32 blocks on one XCD
    int g = xcd + 8 * (sb >> 5);          // graph 0..63
    int nb = (sb & 31) * 32;              // node base within graph
    int tid = threadIdx.x;
    int wid = tid >> 6, lane = tid & 63;
    int nsub = lane >> 4;                 // node slot 0..3
    int j0 = lane & 15;
    int c4 = lane & 15;
    const float4* lsg = ls4 + (size_t)g * NNODE;
    const float4* xg = x4 + (size_t)g * NNODE * 16 + c4;

    // ---------- aggregation phase: 2 iterations of 4 nodes per wave ----------
    for (int it2 = 0; it2 < 2; it2++) {
        __syncthreads();                  // protect prior iteration's s_e/s_src reads from this iter's writes
        int n_l = wid * 8 + it2 * 4 + nsub;   // local row 0..31
        int n_s = nb + n_l;                   // node in graph
        int valid = n_s < NNODE;
        int n_c = valid ? n_s : (NNODE - 1);  // clamped address
        int rs = rowptr_p[n_c];
        int dgp = valid ? (rowptr_p[n_c + 1] - rs) : 0;
        int dg = valid ? deg[n_c] : 0;
        int dg16 = (dgp + 15) & ~15;
        if (dg16 > 64) dg16 = 64;
        if (dgp > 64) dgp = 64;
        if (dg > 64) dg = 64;
        float4 ldv = ld4[(size_t)g * NNODE + n_c];

        // pass A: logits + running max (4-head float4 at s_e[..][j*4])
        float4 mx = make_float4(-1e30f, -1e30f, -1e30f, -1e30f);
        for (int base = 0; base < dg16; base += 16) {
            int j = base + j0;
            int sv = n_c;
            if (j < dgp) sv = csr_src[rs + j];
            s_src[wid][nsub][j] = (unsigned short)sv;
            float4 lo = make_float4(-1e30f, -1e30f, -1e30f, -1e30f);
            if (j < dg) {
                float4 t = lsg[sv];
                t.x += ldv.x; t.y += ldv.y; t.z += ldv.z; t.w += ldv.w;
                t.x = fmaxf(t.x, 0.2f * t.x); t.y = fmaxf(t.y, 0.2f * t.y);
                t.z = fmaxf(t.z, 0.2f * t.z); t.w = fmaxf(t.w, 0.2f * t.w);
                lo = t;
                mx.x = fmaxf(mx.x, lo.x); mx.y = fmaxf(mx.y, lo.y);
                mx.z = fmaxf(mx.z, lo.z); mx.w = fmaxf(mx.w, lo.w);
            }
            *reinterpret_cast<float4*>(&s_e[wid][nsub][j * 4]) = lo;
        }
        #pragma unroll
        for (int o = 1; o < 16; o <<= 1) {
            mx.x = fmaxf(mx.x, __shfl_xor(mx.x, o, 64));
            mx.y = fmaxf(mx.y, __shfl_xor(mx.y, o, 64));
            mx.z = fmaxf(mx.z, __shfl_xor(mx.z, o, 64));
            mx.w = fmaxf(mx.w, __shfl_xor(mx.w, o, 64));
        }
        // pass B: exp + denominator
        float4 den = make_float4(0.f, 0.f, 0.f, 0.f);
        for (int base = 0; base < dg16; base += 16) {
            int j = base + j0;
            float4 e = make_float4(0.f, 0.f, 0.f, 0.f);
            if (j < dg) {
                float4 lo = *reinterpret_cast<const float4*>(&s_e[wid][nsub][j * 4]);
                e.x = __expf(lo.x - mx.x);
                e.y = __expf(lo.y - mx.y);
                e.z = __expf(lo.z - mx.z);
                e.w = __expf(lo.w - mx.w);
            }
            den.x += e.x; den.y += e.y; den.z += e.z; den.w += e.w;
            *reinterpret_cast<float4*>(&s_e[wid][nsub][j * 4]) = e;
        }
        #pragma unroll
        for (int o = 1; o < 16; o <<= 1) {
            den.x += __shfl_xor(den.x, o, 64);
            den.y += __shfl_xor(den.y, o, 64);
            den.z += __shfl_xor(den.z, o, 64);
            den.w += __shfl_xor(den.w, o, 64);
        }
        if (j0 == 0) *reinterpret_cast<float4*>(&s_den[wid][nsub][0]) = den;
        __syncthreads();                  // all s_e/s_den/s_src writes visible before gather

        // gather: lane (nsub,c4) owns one node's col slice, all 4 heads
        float4 a0 = make_float4(0.f, 0.f, 0.f, 0.f);
        float4 a1 = a0, a2 = a0, a3 = a0;
        const float* ep = &s_e[wid][nsub][0];
        const unsigned short* sp = &s_src[wid][nsub][0];
        int dg4 = (dg + 3) & ~3;
        int q = 0;
        for (; q + 8 <= dg4; q += 8) {
            int sj[8]; float4 ev[8], xv[8];
            #pragma unroll
            for (int u = 0; u < 8; u++) sj[u] = sp[q + u];
            #pragma unroll
            for (int u = 0; u < 8; u++) xv[u] = xg[(size_t)sj[u] * 16];
            #pragma unroll
            for (int u = 0; u < 8; u++) ev[u] = *reinterpret_cast<const float4*>(&ep[(q + u) * 4]);
            #pragma unroll
            for (int u = 0; u < 8; u++) {
                a0.x += ev[u].x * xv[u].x; a0.y += ev[u].x * xv[u].y;
                a0.z += ev[u].x * xv[u].z; a0.w += ev[u].x * xv[u].w;
                a1.x += ev[u].y * xv[u].x; a1.y += ev[u].y * xv[u].y;
                a1.z += ev[u].y * xv[u].z; a1.w += ev[u].y * xv[u].w;
                a2.x += ev[u].z * xv[u].x; a2.y += ev[u].z * xv[u].y;
                a2.z += ev[u].z * xv[u].z; a2.w += ev[u].z * xv[u].w;
                a3.x += ev[u].w * xv[u].x; a3.y += ev[u].w * xv[u].y;
                a3.z += ev[u].w * xv[u].z; a3.w += ev[u].w * xv[u].w;
            }
        }
        if (q < dg4) {
            int sj[4]; float4 ev[4], xv[4];
            #pragma unroll
            for (int u = 0; u < 4; u++) sj[u] = sp[q + u];
            #pragma unroll
            for (int u = 0; u < 4; u++) xv[u] = xg[(size_t)sj[u] * 16];
            #pragma unroll
            for (int u = 0; u < 4; u++) ev[u] = *reinterpret_cast<const float4*>(&ep[(q + u) * 4]);
            #pragma unroll
            for (int u = 0; u < 4; u++) {
                a0.x += ev[u].x * xv[u].x; a0.y += ev[u].x * xv[u].y;
                a0.z += ev[u].x * xv[u].z; a0.w += ev[u].x * xv[u].w;
                a1.x += ev[u].y * xv[u].x; a1.y += ev[u].y * xv[u].y;
                a1.z += ev[u].y * xv[u].z; a1.w += ev[u].y * xv[u].w;
                a2.x += ev[u].z * xv[u].x; a2.y += ev[u].z * xv[u].y;
                a2.z += ev[u].z * xv[u].z; a2.w += ev[u].z * xv[u].w;
                a3.x += ev[u].w * xv[u].x; a3.y += ev[u].w * xv[u].y;
                a3.z += ev[u].w * xv[u].z; a3.w += ev[u].w * xv[u].w;
            }
        }
        float4 dv = *reinterpret_cast<const float4*>(&s_den[wid][nsub][0]);
        float i0 = 1.f / (dv.x + 1e-16f), i1 = 1.f / (dv.y + 1e-16f);
        float i2 = 1.f / (dv.z + 1e-16f), i3 = 1.f / (dv.w + 1e-16f);
        a0.x *= i0; a0.y *= i0; a0.z *= i0; a0.w *= i0;
        a1.x *= i1; a1.y *= i1; a1.z *= i1; a1.w *= i1;
        a2.x *= i2; a2.y *= i2; a2.z *= i2; a2.w *= i2;
        a3.x *= i3; a3.y *= i3; a3.z *= i3; a3.w *= i3;
        ushort4 h0 = bfhi4(a0), h1 = bfhi4(a1), h2 = bfhi4(a2), h3 = bfhi4(a3);
        *reinterpret_cast<ushort4*>(&yhs[n_l][0 * 64 + c4 * 4]) = h0;
        *reinterpret_cast<ushort4*>(&yhs[n_l][1 * 64 + c4 * 4]) = h1;
        *reinterpret_cast<ushort4*>(&yhs[n_l][2 * 64 + c4 * 4]) = h2;
        *reinterpret_cast<ushort4*>(&yhs[n_l][3 * 64 + c4 * 4]) = h3;
        *reinterpret_cast<ushort4*>(&yls[n_l][0 * 64 + c4 * 4]) = bflo4(a0, h0);
        *reinterpret_cast<ushort4*>(&yls[n_l][1 * 64 + c4 * 4]) = bflo4(a1, h1);
        *reinterpret_cast<ushort4*>(&yls[n_l][2 * 64 + c4 * 4]) = bflo4(a2, h2);
        *reinterpret_cast<ushort4*>(&yls[n_l][3 * 64 + c4 * 4]) = bflo4(a3, h3);
    }
    __syncthreads();

    // ---------- GEMM phase: wave = rows (wid&1)*16..+16, cols (wid>>1)*32..+32 ----------
    int r0l = (wid & 1) * 16;
    int ch = wid >> 1;
    int arow = lane & 15, kg = lane >> 4;
    f32x4 acc0 = {0.f, 0.f, 0.f, 0.f};
    f32x4 acc1 = {0.f, 0.f, 0.f, 0.f};
    const short8* bh8 = reinterpret_cast<const short8*>(wph) + lane;
    const short8* bl8 = reinterpret_cast<const short8*>(wpl) + lane;
    #pragma unroll
    for (int ks = 0; ks < 8; ks++) {
        short8 ah = *reinterpret_cast<const short8*>(&yhs[r0l + arow][ks * 32 + kg * 8]);
        short8 al = *reinterpret_cast<const short8*>(&yls[r0l + arow][ks * 32 + kg * 8]);
        #pragma unroll
        for (int ctl = 0; ctl < 2; ctl++) {
            int ctg = ch * 2 + ctl;
            short8 bh = bh8[(size_t)(ks * 4 + ctg) * 64];
            short8 bl = bl8[(size_t)(ks * 4 + ctg) * 64];
            f32x4* ac = ctl ? &acc1 : &acc0;
            *ac = __builtin_amdgcn_mfma_f32_16x16x32_bf16(ah, bh, *ac, 0, 0, 0);
            *ac = __builtin_amdgcn_mfma_f32_16x16x32_bf16(ah, bl, *ac, 0, 0, 0);
            *ac = __builtin_amdgcn_mfma_f32_16x16x32_bf16(al, bh, *ac, 0, 0, 0);
        }
    }

    // epilogue: bias + ELU + store xout; D layout col=lane&15, row=(lane>>4)*4+reg
    float ev2[2][4];
    #pragma unroll
    for (int ctl = 0; ctl < 2; ctl++) {
        int c = (ch * 2 + ctl) * 16 + arow;
        float bc = bg[c];
        f32x4 a = ctl ? acc1 : acc0;
        #pragma unroll
        for (int r = 0; r < 4; r++) {
            int node = nb + r0l + kg * 4 + r;
            float v = a[r] * 0.25f + bc;
            float e = v > 0.f ? v : expm1f(v);
            ev2[ctl][r] = e;
            if (node < NNODE)
                xout[((size_t)g * NNODE + node) * HID + c] = e;
        }
    }
    if (wa4) {
        float* s_part = &s_e[0][0][0];    // [2][32][8] floats, s_e dead after barrier above
        __syncthreads();                  // ensure all waves done with s_e (gather) before aliasing
        #pragma unroll
        for (int r = 0; r < 4; r++) {
            float4 pls = make_float4(0.f, 0.f, 0.f, 0.f);
            float4 pld = make_float4(0.f, 0.f, 0.f, 0.f);
            #pragma unroll
            for (int ctl = 0; ctl < 2; ctl++) {
                int c = (ch * 2 + ctl) * 16 + arow;
                float e = ev2[ctl][r];
                float4 wa_c = wa4[c];
                float4 wd_c = wd4[c];
                pls.x += e * wa_c.x; pls.y += e * wa_c.y;
                pls.z += e * wa_c.z; pls.w += e * wa_c.w;
                pld.x += e * wd_c.x; pld.y += e * wd_c.y;
                pld.z += e * wd_c.z; pld.w += e * wd_c.w;
            }
            #pragma unroll
            for (int o = 1; o < 16; o <<= 1) {
                pls.x += __shfl_xor(pls.x, o, 64); pls.y += __shfl_xor(pls.y, o, 64);
                pls.z += __shfl_xor(pls.z, o, 64); pls.w += __shfl_xor(pls.w, o, 64);
                pld.x += __shfl_xor(pld.x, o, 64); pld.y += __shfl_xor(pld.y, o, 64);
                pld.z += __shfl_xor(pld.z, o, 64); pld.w += __shfl_xor(pld.w, o, 64);
            }
            if (arow == 0) {
                int rl = r0l + kg * 4 + r;
                float4* p = reinterpret_cast<float4*>(&s_part[(ch * 32 + rl) * 8]);
                p[0] = pls; p[1] = pld;
            }
        }
        __syncthreads();
        int rl = tid >> 3, cc = tid & 7;  // 32 rows x 8 components
        int node = nb + rl;
        if (node < NNODE) {
            float v = s_part[rl * 8 + cc] + s_part[(32 + rl) * 8 + cc];
            float* dst = (cc < 4) ? reinterpret_cast<float*>(lso4) : reinterpret_cast<float*>(ldo4);
            dst[((size_t)g * NNODE + node) * 4 + (cc & 3)] = v;
        }
    }
}

// ---------------- GRU input GEMM: 500 K-slices, full 64x192 tile/block, no atomics ----------------
__global__ __launch_bounds__(256) void k_gi_gemm(const float* __restrict__ x, const float* __restrict__ W_ih,
                                                 float* __restrict__ gip) {
    __shared__ float xs[32 * 68];    // [kk][row], pitch 68
    __shared__ float ws[32 * 196];   // [kk][col 0..191], pitch 196
    int k0 = blockIdx.x * GIK;
    int tid = threadIdx.x;
    int lane = tid & 63;
    int wv = tid >> 6;
    int tx = tid & 15, ty = tid >> 4;
    float4 accs[4][3];
    #pragma unroll
    for (int i = 0; i < 4; i++)
        #pragma unroll
        for (int j = 0; j < 3; j++) accs[i][j] = make_float4(0.f, 0.f, 0.f, 0.f);

    for (int kt = 0; kt < GIK / 32; kt++) {
        int kb = k0 + kt * 32;
        #pragma unroll
        for (int it = 0; it < 2; it++) {
            int kq = wv + 4 * it;
            float4 v = *reinterpret_cast<const float4*>(&x[(size_t)lane * KGI + kb + kq * 4]);
            int k = kq * 4;
            xs[(k + 0) * 68 + lane] = v.x;
            xs[(k + 1) * 68 + lane] = v.y;
            xs[(k + 2) * 68 + lane] = v.z;
            xs[(k + 3) * 68 + lane] = v.w;
        }
        #pragma unroll
        for (int cg = 0; cg < 3; cg++) {
            #pragma unroll
            for (int it = 0; it < 2; it++) {
                int kq = wv + 4 * it;
                int c = cg * 64 + lane;
                float4 v = *reinterpret_cast<const float4*>(&W_ih[(size_t)c * KGI + kb + kq * 4]);
                int k = kq * 4;
                ws[(k + 0) * 196 + c] = v.x;
                ws[(k + 1) * 196 + c] = v.y;
                ws[(k + 2) * 196 + c] = v.z;
                ws[(k + 3) * 196 + c] = v.w;
            }
        }
        __syncthreads();
        for (int kk = 0; kk < 32; kk++) {
            float4 xv = *reinterpret_cast<const float4*>(&xs[kk * 68 + ty * 4]);
            float4 w0 = *reinterpret_cast<const float4*>(&ws[kk * 196 + tx * 4]);
            float4 w1 = *reinterpret_cast<const float4*>(&ws[kk * 196 + 64 + tx * 4]);
            float4 w2 = *reinterpret_cast<const float4*>(&ws[kk * 196 + 128 + tx * 4]);
            #pragma unroll
            for (int i = 0; i < 4; i++) {
                float xi = (i == 0) ? xv.x : (i == 1) ? xv.y : (i == 2) ? xv.z : xv.w;
                accs[i][0].x += xi * w0.x; accs[i][0].y += xi * w0.y; accs[i][0].z += xi * w0.z; accs[i][0].w += xi * w0.w;
                accs[i][1].x += xi * w1.x; accs[i][1].y += xi * w1.y; accs[i][1].z += xi * w1.z; accs[i][1].w += xi * w1.w;
                accs[i][2].x += xi * w2.x; accs[i][2].y += xi * w2.y; accs[i][2].z += xi * w2.z; accs[i][2].w += xi * w2.w;
            }
        }
        __syncthreads();
    }
    float* out = gip + (size_t)blockIdx.x * GOSZ;
    #pragma unroll
    for (int i = 0; i < 4; i++)
        #pragma unroll
        for (int j = 0; j < 3; j++)
            *reinterpret_cast<float4*>(&out[(ty * 4 + i) * GOUT + j * 64 + tx * 4]) = accs[i][j];
}

__global__ void k_gi_reduce1(const float* __restrict__ gip, float* __restrict__ gip2) {
    int idx = blockIdx.x * 256 + threadIdx.x;     // 0..GOSZ-1
    const float* p = gip + (size_t)blockIdx.y * 50 * GOSZ + idx;
    float a = 0.f;
    #pragma unroll 5
    for (int s = 0; s < 50; s++) a += p[(size_t)s * GOSZ];
    gip2[blockIdx.y * GOSZ + idx] = a;
}

__global__ void k_gi_reduce2(const float* __restrict__ gip2, const float* __restrict__ b_ih,
                             float* __restrict__ gi) {
    int idx = blockIdx.x * 256 + threadIdx.x;
    float a = b_ih[idx % GOUT];
    #pragma unroll
    for (int y = 0; y < 10; y++) a += gip2[(size_t)y * GOSZ + idx];
    gi[idx] = a;
}

// ---------------- GRU scan: one block per batch, W_hh row in registers, LDS broadcast hs ----------------
__global__ __launch_bounds__(192) void k_gru(const float* __restrict__ gi, const float* __restrict__ W_hh,
                                             const float* __restrict__ b_hh, float* __restrict__ hT) {
    __shared__ float hs[64];
    __shared__ float gh[192];
    int j = threadIdx.x;      // 0..191
    int b = blockIdx.x;       // 0..3
    float wrow[64];
    #pragma unroll
    for (int q = 0; q < 16; q++) {
        float4 v = *reinterpret_cast<const float4*>(&W_hh[(size_t)j * 64 + q * 4]);
        wrow[q * 4 + 0] = v.x; wrow[q * 4 + 1] = v.y;
        wrow[q * 4 + 2] = v.z; wrow[q * 4 + 3] = v.w;
    }
    float bj = b_hh[j];
    if (j < 64) hs[j] = 0.f;
    __syncthreads();
    for (int t = 0; t < TT; t++) {
        float a0 = 0.f, a1 = 0.f, a2 = 0.f, a3 = 0.f;
        #pragma unroll
        for (int q = 0; q < 16; q++) {
            float4 h4 = *reinterpret_cast<const float4*>(&hs[q * 4]);   // broadcast read
            a0 += h4.x * wrow[q * 4 + 0];
            a1 += h4.y * wrow[q * 4 + 1];
            a2 += h4.z * wrow[q * 4 + 2];
            a3 += h4.w * wrow[q * 4 + 3];
        }
        gh[j] = bj + ((a0 + a1) + (a2 + a3));
        __syncthreads();
        if (j < 64) {
            int row = (b * TT + t) * GOUT;
            float ir = gi[row + j], iz = gi[row + 64 + j], in_ = gi[row + 128 + j];
            float r = 1.f / (1.f + expf(-(ir + gh[j])));
            float z = 1.f / (1.f + expf(-(iz + gh[64 + j])));
            float nv = tanhf(in_ + r * gh[128 + j]);
            hs[j] = (1.f - z) * nv + z * hs[j];
        }
        __syncthreads();
    }
    if (j < 64) hT[b * 64 + j] = hs[j];
}

// ---------------- final FC ----------------
__global__ void k_final(const float* __restrict__ hT, const float* __restrict__ W_fc,
                        const float* __restrict__ b_fc, float* __restrict__ out) {
    int idx = blockIdx.x * 256 + threadIdx.x;
    if (idx >= NB * NNODE) return;
    int b = idx / NNODE, n = idx % NNODE;
    float acc = b_fc[n];
    #pragma unroll
    for (int c = 0; c < HID; c++) acc += hT[b * HID + c] * W_fc[c * NNODE + n];
    out[idx] = acc;
}

extern "C" void kernel_launch(void* const* d_in, const int* in_sizes, int n_in,
                              void* d_out, int out_size, void* d_ws, size_t ws_size,
                              hipStream_t stream) {
    const float* x_seq  = (const float*)d_in[0];
    const int*   eidx   = (const int*)  d_in[1];
    // d_in[2] edge_weight: unused by GATConv
    const float* W_in   = (const float*)d_in[3];
    const float* b_in   = (const float*)d_in[4];
    const float* Wg     = (const float*)d_in[5];
    const float* a_src  = (const float*)d_in[6];
    const float* a_dst  = (const float*)d_in[7];
    const float* bg     = (const float*)d_in[8];
    const float* W_ih   = (const float*)d_in[9];
    const float* W_hh   = (const float*)d_in[10];
    const float* b_ih   = (const float*)d_in[11];
    const float* b_hh   = (const float*)d_in[12];
    const float* W_fc   = (const float*)d_in[13];
    const float* b_fc   = (const float*)d_in[14];
    float* out = (float*)d_out;

    float* wsf = (float*)d_ws;
    size_t off = 0;
    float* x0a    = wsf + off; off += (size_t)ROWS * HID;       // 4,096,000 floats
    float* x0b    = wsf + off; off += (size_t)ROWS * HID;       // 4,096,000
    float* lsa    = wsf + off; off += (size_t)ROWS * HEADS;     // 256,000
    float* ldaf   = wsf + off; off += (size_t)ROWS * HEADS;
    float* lsbf   = wsf + off; off += (size_t)ROWS * HEADS;
    float* ldbf   = wsf + off; off += (size_t)ROWS * HEADS;
    float* wab    = wsf + off; off += NL * HCOL;                // 1,280
    float* wdb    = wsf + off; off += NL * HCOL;
    float* gib    = wsf + off; off += GOSZ;                     // 12,288
    float* hTb    = wsf + off; off += 256;
    u16* wphb     = (u16*)(wsf + off); off += NL * WPSZ / 2;    // 40,960 floats
    u16* wplb     = (u16*)(wsf + off); off += NL * WPSZ / 2;
    float* gip    = wsf + off; off += (size_t)KSPLIT * GOSZ;    // 6,144,000
    float* gip2   = wsf + off; off += 10 * GOSZ;                // 122,880
    int* ib = (int*)(wsf + off);
    int* src_e    = ib;          ib += EP;
    int* dst_e    = ib;          ib += EP;
    int* rowptr_p = ib;          ib += NNODE + 1;
    int* csr_src  = ib;          ib += EPAD;
    int* deg      = ib;          ib += NNODE;
    int* fill     = ib;          ib += NNODE;

    k_build_edges<<<(EP + 255) / 256, 256, 0, stream>>>(eidx, src_e, dst_e, deg, fill);
    k_csr_count<<<(EP + 255) / 256, 256, 0, stream>>>(dst_e, deg);
    k_csr_scan<<<1, 256, 0, stream>>>(deg, rowptr_p);
    k_csr_fill<<<(EP + 255) / 256, 256, 0, stream>>>(src_e, dst_e, rowptr_p, deg, fill, csr_src);

    k_wa<<<10, 256, 0, stream>>>(Wg, a_src, a_dst, wab, wdb);
    k_wpack<<<(NL * WPSZ + 255) / 256, 256, 0, stream>>>(Wg, wphb, wplb);

    k_input_fc<<<ROWS * 16 / 256, 256, 0, stream>>>(
        x_seq, (const float4*)W_in, (const float4*)b_in,
        (const float4*)wab, (const float4*)wdb, (float4*)x0a, (float4*)lsa, (float4*)ldaf);

    float* xc = x0a;  float* xn = x0b;
    float* lsc = lsa; float* ldc = ldaf;
    float* lsn = lsbf; float* ldn = ldbf;
    for (int l = 0; l < NL; l++) {
        const float4* wa_next = (l + 1 < NL) ? (const float4*)(wab + (size_t)(l + 1) * HCOL) : nullptr;
        const float4* wd_next = (l + 1 < NL) ? (const float4*)(wdb + (size_t)(l + 1) * HCOL) : nullptr;
        k_gat_fused<<<2048, 256, 0, stream>>>(
            (const float4*)xc, (const float4*)lsc, (const float4*)ldc,
            rowptr_p, csr_src, deg,
            wphb + (size_t)l * WPSZ, wplb + (size_t)l * WPSZ, bg + (size_t)l * HID,
            xn, wa_next, wd_next, (float4*)lsn, (float4*)ldn);
        float* t;
        t = xc; xc = xn; xn = t;
        t = lsc; lsc = lsn; lsn = t;
        t = ldc; ldc = ldn; ldn = t;
    }

    k_gi_gemm<<<KSPLIT, 256, 0, stream>>>(xc, W_ih, gip);
    k_gi_reduce1<<<dim3(GOSZ / 256, 10), 256, 0, stream>>>(gip, gip2);
    k_gi_reduce2<<<GOSZ / 256, 256, 0, stream>>>(gip2, b_ih, gib);
    k_gru<<<4, 192, 0, stream>>>(gib, W_hh, b_hh, hTb);
    k_final<<<(NB * NNODE + 255) / 256, 256, 0, stream>>>(hTb, W_fc, b_fc, out);
}